// Round 18
// baseline (10463.211 us; speedup 1.0000x reference)
//
#include <hip/hip_runtime.h>
#include <cstdint>

#define EMBD 300
#define GNUM 2048
#define LSEM 10
#define VSEM 30
#define NLAY 5
#define GRAM_KB 24
#define RB2 512

typedef __attribute__((ext_vector_type(8))) short short8v;
typedef __attribute__((ext_vector_type(4))) float f32x4;

// exact fp32 -> 3x bf16 split (integer RNE; weight pre-split)
__device__ __forceinline__ void split3(float x, short& h1, short& h2, short& h3) {
  unsigned u = __float_as_uint(x);
  unsigned uh = (u + 0x7FFFu + ((u >> 16) & 1u)) & 0xFFFF0000u;
  h1 = (short)(uh >> 16);
  float r = x - __uint_as_float(uh);
  unsigned v = __float_as_uint(r);
  unsigned vh = (v + 0x7FFFu + ((v >> 16) & 1u)) & 0xFFFF0000u;
  h2 = (short)(vh >> 16);
  float r2 = r - __uint_as_float(vh);
  unsigned w = __float_as_uint(r2);
  unsigned wh = (w + 0x7FFFu + ((w >> 16) & 1u)) & 0xFFFF0000u;
  h3 = (short)(wh >> 16);
}

// packed fp32x2 -> bf16x2 (1 HW instr)
__device__ __forceinline__ unsigned cvt_pk_bf16(float lo, float hi) {
  unsigned r;
  asm("v_cvt_pk_bf16_f32 %0, %1, %2" : "=v"(r) : "v"(lo), "v"(hi));
  return r;
}

// split a PAIR of fp32 into 3 packed-bf16 limbs (residuals exact)
__device__ __forceinline__ void split3_pair(float x0, float x1,
                                            unsigned& u1, unsigned& u2, unsigned& u3) {
  u1 = cvt_pk_bf16(x0, x1);
  float r0 = x0 - __uint_as_float(u1 << 16);
  float r1 = x1 - __uint_as_float(u1 & 0xFFFF0000u);
  u2 = cvt_pk_bf16(r0, r1);
  float s0 = r0 - __uint_as_float(u2 << 16);
  float s1 = r1 - __uint_as_float(u2 & 0xFFFF0000u);
  u3 = cvt_pk_bf16(s0, s1);
}

// ---------------- diagnostics / utility ----------------
__global__ void k_diag(float* __restrict__ p, int n, float v) {
  int i = blockIdx.x * blockDim.x + threadIdx.x;
  if (i < n) p[i] = v;
}

__global__ void k_zero(float* __restrict__ p, int n) {
  int i = blockIdx.x * blockDim.x + threadIdx.x;
  if (i < n) p[i] = 0.f;
}

__global__ void k_seti(int* __restrict__ p, int n, int v) {
  int i = blockIdx.x * blockDim.x + threadIdx.x;
  if (i < n) p[i] = v;
}

// offsets via binary search (batch is sorted)
__global__ void k_offsets(const int* __restrict__ batch, int N, int* __restrict__ off) {
  int g = blockIdx.x * blockDim.x + threadIdx.x;
  if (g > GNUM) return;
  int lo = 0, hi = N;
  while (lo < hi) { int mid = (lo + hi) >> 1; if (batch[mid] < g) lo = mid + 1; else hi = mid; }
  off[g] = lo;
}

// ---------------- CSR build ----------------
__global__ void k_deg(const int* __restrict__ dst, int E, int* __restrict__ deg) {
  int e = blockIdx.x * blockDim.x + threadIdx.x;
  if (e < E) atomicAdd(&deg[dst[e]], 1);
}

__global__ void k_scan1(const int* __restrict__ deg, int N,
                        int* __restrict__ incl, int* __restrict__ part) {
  __shared__ int s[256];
  int tid = threadIdx.x;
  int i = blockIdx.x * 256 + tid;
  int v = (i < N) ? deg[i] : 0;
  s[tid] = v; __syncthreads();
  for (int o = 1; o < 256; o <<= 1) {
    int t = (tid >= o) ? s[tid - o] : 0;
    __syncthreads();
    s[tid] += t;
    __syncthreads();
  }
  if (i < N) incl[i] = s[tid];
  if (tid == 255) part[blockIdx.x] = s[255];
}

__global__ void k_scan2(int* __restrict__ part, int nb) {
  __shared__ int s[512];
  int t = threadIdx.x;
  if (nb <= 512) {
    int v = (t < nb) ? part[t] : 0;
    s[t] = v; __syncthreads();
    for (int o = 1; o < 512; o <<= 1) {
      int u = (t >= o) ? s[t - o] : 0;
      __syncthreads();
      s[t] += u;
      __syncthreads();
    }
    if (t < nb) part[t] = s[t] - v;
  } else if (t == 0) {
    int run = 0;
    for (int i = 0; i < nb; i++) { int x = part[i]; part[i] = run; run += x; }
  }
}

__global__ void k_scan3(const int* __restrict__ deg, const int* __restrict__ incl,
                        const int* __restrict__ part, int N, int E, int* __restrict__ off2) {
  int i = blockIdx.x * blockDim.x + threadIdx.x;
  if (i < N) off2[i] = part[i >> 8] + incl[i] - deg[i];
  if (i == 0) off2[N] = E;
}

__global__ void k_copyi(const int* __restrict__ a, int* __restrict__ b, int n) {
  int i = blockIdx.x * blockDim.x + threadIdx.x;
  if (i < n) b[i] = a[i];
}

__global__ void k_fill(const int* __restrict__ dst, int E,
                       int* __restrict__ cur, int* __restrict__ eix) {
  int e = blockIdx.x * blockDim.x + threadIdx.x;
  if (e >= E) return;
  int p = atomicAdd(&cur[dst[e]], 1);
  eix[p] = e;
}

// ---------------- hl / tacc ----------------
template<bool FIRST>
__global__ void k_hl(const float* __restrict__ aemb, const int* __restrict__ x_idx,
                     const float* __restrict__ scale, const float* __restrict__ shift,
                     const int* __restrict__ batch, const float* __restrict__ vn,
                     const float* __restrict__ epsArr, int l,
                     float* pt, float* __restrict__ hl, int N)
{
  int i = blockIdx.x;
  int c = threadIdx.x;
  if (c >= EMBD) return;
  float x;
  if (FIRST) {
    x = aemb[(size_t)x_idx[i] * EMBD + c];
  } else {
    x = pt[(size_t)i * EMBD + c];
    x = fmaxf(fmaf(x, scale[c], shift[c]), 0.f);
  }
  float h = x + vn[(size_t)batch[i] * EMBD + c];
  hl[(size_t)i * EMBD + c] = h;
  pt[(size_t)i * EMBD + c] = (1.f + epsArr[l]) * h;
}

// ---------------- CSR gather ----------------
__global__ void k_gather(const int* __restrict__ off2, const int* __restrict__ eix,
                         const int* __restrict__ src, const int* __restrict__ eattr,
                         const float* __restrict__ hl, const float* __restrict__ bond,
                         float* __restrict__ tacc, int N)
{
  int node = blockIdx.x * 4 + (threadIdx.x >> 6);
  int lane = threadIdx.x & 63;
  if (node >= N) return;
  int p0 = off2[node], p1 = off2[node + 1];
  if (p0 == p1) return;
  float acc[5] = {0.f, 0.f, 0.f, 0.f, 0.f};
  for (int p = p0; p < p1; p++) {
    int e = eix[p];
    int s = src[e], a = eattr[e];
    const float* hr = hl + (size_t)s * EMBD;
    const float* br = bond + (size_t)a * EMBD;
    #pragma unroll
    for (int q = 0; q < 5; q++) {
      int c = lane + q * 64;
      if (c < EMBD) {
        float v = hr[c] + br[c];
        acc[q] += fmaxf(v, 0.f);
      }
    }
  }
  float* tr = tacc + (size_t)node * EMBD;
  #pragma unroll
  for (int q = 0; q < 5; q++) {
    int c = lane + q * 64;
    if (c < EMBD) tr[c] += acc[q];
  }
}

// ---------------- W split: [K][M] fp32 -> 3 bf16 planes [M][Kpad] ----------------
__global__ void k_splitW(const float* __restrict__ W, int K, int Kpad, int M,
                         short* __restrict__ planes)
{
  int idx = blockIdx.x * 256 + threadIdx.x;
  if (idx >= M * Kpad) return;
  int m = idx / Kpad, k = idx - m * Kpad;
  float x = (k < K) ? W[(size_t)k * M + m] : 0.f;
  short h1, h2, h3; split3(x, h1, h2, h3);
  size_t ps = (size_t)M * Kpad;
  planes[idx] = h1; planes[ps + idx] = h2; planes[2 * ps + idx] = h3;
}

// ---------------- split-bf16 MFMA GEMM, CT*64-col tiles (proven); optional fused col-stats ----------------
template<int CT, bool AFUSE, bool STATS>
__global__ __launch_bounds__(256) void k_mgemm(
    const float* __restrict__ A, const short* __restrict__ Wp,
    const float* __restrict__ bias, float* __restrict__ C,
    int n, int K, int Kpad, int M,
    const float* __restrict__ ascale, const float* __restrict__ ashift,
    double* __restrict__ psum, double* __restrict__ psq)
{
  __shared__ __align__(16) short lsA[3][64][40];
  __shared__ __align__(16) short lsB[3][CT * 64][40];
  int tid = threadIdx.x;
  int row0 = blockIdx.x * 64;
  int col0 = blockIdx.y * (CT * 64);
  int l = tid & 63, wid = tid >> 6;
  int wr = wid >> 1, wc = wid & 1;
  int lr = l & 15, kb = (l >> 4) * 8, rbase = (l >> 4) * 4;
  int sar = tid >> 2;
  int sak = (tid & 3) * 8;
  size_t planeSz = (size_t)M * Kpad;

  f32x4 acc[2][CT * 2];
  #pragma unroll
  for (int i = 0; i < 2; i++)
    #pragma unroll
    for (int j = 0; j < CT * 2; j++) acc[i][j] = (f32x4){0.f, 0.f, 0.f, 0.f};

  for (int k0 = 0; k0 < Kpad; k0 += 32) {
    {
      int gr = row0 + sar;
      int kbase = k0 + sak;
      float x[8];
      if (gr < n && kbase + 7 < K) {
        const float* ap = A + (size_t)gr * K + kbase;
        float4 u0 = *reinterpret_cast<const float4*>(ap);
        float4 u1 = *reinterpret_cast<const float4*>(ap + 4);
        x[0] = u0.x; x[1] = u0.y; x[2] = u0.z; x[3] = u0.w;
        x[4] = u1.x; x[5] = u1.y; x[6] = u1.z; x[7] = u1.w;
        if (AFUSE) {
          float4 sc0 = *reinterpret_cast<const float4*>(ascale + kbase);
          float4 sc1 = *reinterpret_cast<const float4*>(ascale + kbase + 4);
          float4 sf0 = *reinterpret_cast<const float4*>(ashift + kbase);
          float4 sf1 = *reinterpret_cast<const float4*>(ashift + kbase + 4);
          x[0] = fmaxf(fmaf(x[0], sc0.x, sf0.x), 0.f);
          x[1] = fmaxf(fmaf(x[1], sc0.y, sf0.y), 0.f);
          x[2] = fmaxf(fmaf(x[2], sc0.z, sf0.z), 0.f);
          x[3] = fmaxf(fmaf(x[3], sc0.w, sf0.w), 0.f);
          x[4] = fmaxf(fmaf(x[4], sc1.x, sf1.x), 0.f);
          x[5] = fmaxf(fmaf(x[5], sc1.y, sf1.y), 0.f);
          x[6] = fmaxf(fmaf(x[6], sc1.z, sf1.z), 0.f);
          x[7] = fmaxf(fmaf(x[7], sc1.w, sf1.w), 0.f);
        }
      } else {
        #pragma unroll
        for (int j = 0; j < 8; j++) {
          int k = kbase + j;
          float v = 0.f;
          if (gr < n && k < K) {
            v = A[(size_t)gr * K + k];
            if (AFUSE) v = fmaxf(fmaf(v, ascale[k], ashift[k]), 0.f);
          }
          x[j] = v;
        }
      }
      uint4 q1, q2, q3;
      unsigned* p1 = (unsigned*)&q1; unsigned* p2 = (unsigned*)&q2; unsigned* p3 = (unsigned*)&q3;
      #pragma unroll
      for (int j = 0; j < 4; j++) split3_pair(x[2 * j], x[2 * j + 1], p1[j], p2[j], p3[j]);
      *reinterpret_cast<uint4*>(&lsA[0][sar][sak]) = q1;
      *reinterpret_cast<uint4*>(&lsA[1][sar][sak]) = q2;
      *reinterpret_cast<uint4*>(&lsA[2][sar][sak]) = q3;
    }
    if constexpr (CT == 2) {
      int sbc = tid >> 1;
      int sbk = (tid & 1) * 16;
      int gc = col0 + sbc;
      #pragma unroll
      for (int p = 0; p < 3; p++) {
        short8v v0, v1;
        if (gc < M) {
          const short* bp = Wp + (size_t)p * planeSz + (size_t)gc * Kpad + k0 + sbk;
          v0 = *reinterpret_cast<const short8v*>(bp);
          v1 = *reinterpret_cast<const short8v*>(bp + 8);
        } else {
          #pragma unroll
          for (int j = 0; j < 8; j++) { v0[j] = 0; v1[j] = 0; }
        }
        *reinterpret_cast<short8v*>(&lsB[p][sbc][sbk]) = v0;
        *reinterpret_cast<short8v*>(&lsB[p][sbc][sbk + 8]) = v1;
      }
    } else {
      int sbc = tid >> 2;
      int sbk = (tid & 3) * 8;
      int gc = col0 + sbc;
      #pragma unroll
      for (int p = 0; p < 3; p++) {
        short8v v0;
        if (gc < M) {
          const short* bp = Wp + (size_t)p * planeSz + (size_t)gc * Kpad + k0 + sbk;
          v0 = *reinterpret_cast<const short8v*>(bp);
        } else {
          #pragma unroll
          for (int j = 0; j < 8; j++) v0[j] = 0;
        }
        *reinterpret_cast<short8v*>(&lsB[p][sbc][sbk]) = v0;
      }
    }
    __syncthreads();
    short8v fa[3][2];
    #pragma unroll
    for (int p = 0; p < 3; p++)
      #pragma unroll
      for (int rf = 0; rf < 2; rf++)
        fa[p][rf] = *reinterpret_cast<const short8v*>(&lsA[p][wr * 32 + rf * 16 + lr][kb]);
    #pragma unroll
    for (int cf = 0; cf < CT * 2; cf++) {
      int bcol = wc * (CT * 32) + cf * 16 + lr;
      short8v fb0 = *reinterpret_cast<const short8v*>(&lsB[0][bcol][kb]);
      short8v fb1 = *reinterpret_cast<const short8v*>(&lsB[1][bcol][kb]);
      short8v fb2 = *reinterpret_cast<const short8v*>(&lsB[2][bcol][kb]);
      #pragma unroll
      for (int rf = 0; rf < 2; rf++) {
        f32x4 a = acc[rf][cf];
        a = __builtin_amdgcn_mfma_f32_16x16x32_bf16(fa[0][rf], fb0, a, 0, 0, 0);
        a = __builtin_amdgcn_mfma_f32_16x16x32_bf16(fa[0][rf], fb1, a, 0, 0, 0);
        a = __builtin_amdgcn_mfma_f32_16x16x32_bf16(fa[1][rf], fb0, a, 0, 0, 0);
        a = __builtin_amdgcn_mfma_f32_16x16x32_bf16(fa[1][rf], fb1, a, 0, 0, 0);
        a = __builtin_amdgcn_mfma_f32_16x16x32_bf16(fa[0][rf], fb2, a, 0, 0, 0);
        a = __builtin_amdgcn_mfma_f32_16x16x32_bf16(fa[2][rf], fb0, a, 0, 0, 0);
        acc[rf][cf] = a;
      }
    }
    __syncthreads();
  }
  #pragma unroll
  for (int rf = 0; rf < 2; rf++) {
    #pragma unroll
    for (int cf = 0; cf < CT * 2; cf++) {
      int col = col0 + wc * (CT * 32) + cf * 16 + lr;
      if (col >= M) continue;
      float bv = bias[col];
      #pragma unroll
      for (int r = 0; r < 4; r++) {
        int row = row0 + wr * 32 + rf * 16 + rbase + r;
        if (row < n) C[(size_t)row * M + col] = acc[rf][cf][r] + bv;
      }
    }
  }
  // ---- fused column stats (node-BN): per-block fp64 partials, += across sequential chunks ----
  if constexpr (STATS) {
    __shared__ double smd[8][64];
    int g8 = wr * 4 + (l >> 4);     // 0..7 row-group within column
    #pragma unroll
    for (int cf = 0; cf < 2; cf++) {
      int c = wc * 32 + cf * 16 + lr;     // 0..63 local col
      int gcol = col0 + c;
      double fs = 0.0, fq = 0.0;
      if (gcol < M) {
        float bv = bias[gcol];
        #pragma unroll
        for (int rf = 0; rf < 2; rf++)
          #pragma unroll
          for (int r = 0; r < 4; r++) {
            int row = row0 + wr * 32 + rf * 16 + rbase + r;
            if (row < n) {
              double x = (double)(acc[rf][cf][r] + bv);
              fs += x; fq += x * x;
            }
          }
      }
      __syncthreads();
      smd[g8][c] = fs;
      __syncthreads();
      if (g8 == 0 && gcol < M) {
        double S = 0.0;
        #pragma unroll
        for (int t = 0; t < 8; t++) S += smd[t][c];
        psum[(size_t)blockIdx.x * M + gcol] += S;
      }
      __syncthreads();
      smd[g8][c] = fq;
      __syncthreads();
      if (g8 == 0 && gcol < M) {
        double Q = 0.0;
        #pragma unroll
        for (int t = 0; t < 8; t++) Q += smd[t][c];
        psq[(size_t)blockIdx.x * M + gcol] += Q;
      }
      __syncthreads();
    }
  }
}

// ---------------- MFMA Gram ----------------
__global__ __launch_bounds__(256) void k_mgram(const float* __restrict__ A, int N,
                                               double* __restrict__ gpart)
{
  int bx = blockIdx.x;
  int ti = 0;
  {
    const int o1 = 5, o2 = 9, o3 = 12, o4 = 14;
    if (bx >= o1) ti = 1;
    if (bx >= o2) ti = 2;
    if (bx >= o3) ti = 3;
    if (bx >= o4) ti = 4;
  }
  const int offs[5] = {0, 5, 9, 12, 14};
  int tj = ti + (bx - offs[ti]);
  int I = ti * 64, J = tj * 64;
  __shared__ __align__(16) short lsI[3][64][40];
  __shared__ __align__(16) short lsJ[3][64][40];
  int tid = threadIdx.x;
  int l = tid & 63, wid = tid >> 6;
  int wr = wid >> 1, wc = wid & 1;
  int lr = l & 15, kb = (l >> 4) * 8, rbase = (l >> 4) * 4;
  int sr = tid & 31;
  int sc0 = (tid >> 5) * 8;

  f32x4 acc[2][2];
  #pragma unroll
  for (int i = 0; i < 2; i++)
    #pragma unroll
    for (int j = 0; j < 2; j++) acc[i][j] = (f32x4){0.f, 0.f, 0.f, 0.f};

  for (int r0 = blockIdx.y * 32; r0 < N; r0 += gridDim.y * 32) {
    int gr = r0 + sr;
    float xi[8], xj[8];
    {
      int ci = I + sc0;
      if (gr < N && ci + 7 < EMBD) {
        const float* ap = A + (size_t)gr * EMBD + ci;
        float4 u0 = *reinterpret_cast<const float4*>(ap);
        float4 u1 = *reinterpret_cast<const float4*>(ap + 4);
        xi[0] = u0.x; xi[1] = u0.y; xi[2] = u0.z; xi[3] = u0.w;
        xi[4] = u1.x; xi[5] = u1.y; xi[6] = u1.z; xi[7] = u1.w;
      } else {
        #pragma unroll
        for (int j = 0; j < 8; j++) {
          int c = ci + j;
          xi[j] = (gr < N && c < EMBD) ? A[(size_t)gr * EMBD + c] : 0.f;
        }
      }
      int cj = J + sc0;
      if (gr < N && cj + 7 < EMBD) {
        const float* ap = A + (size_t)gr * EMBD + cj;
        float4 u0 = *reinterpret_cast<const float4*>(ap);
        float4 u1 = *reinterpret_cast<const float4*>(ap + 4);
        xj[0] = u0.x; xj[1] = u0.y; xj[2] = u0.z; xj[3] = u0.w;
        xj[4] = u1.x; xj[5] = u1.y; xj[6] = u1.z; xj[7] = u1.w;
      } else {
        #pragma unroll
        for (int j = 0; j < 8; j++) {
          int c = cj + j;
          xj[j] = (gr < N && c < EMBD) ? A[(size_t)gr * EMBD + c] : 0.f;
        }
      }
    }
    #pragma unroll
    for (int j = 0; j < 8; j++) {
      short a1, a2, a3; split3(xi[j], a1, a2, a3);
      lsI[0][sc0 + j][sr] = a1; lsI[1][sc0 + j][sr] = a2; lsI[2][sc0 + j][sr] = a3;
      short b1, b2, b3; split3(xj[j], b1, b2, b3);
      lsJ[0][sc0 + j][sr] = b1; lsJ[1][sc0 + j][sr] = b2; lsJ[2][sc0 + j][sr] = b3;
    }
    __syncthreads();
    short8v fa[3][2];
    #pragma unroll
    for (int p = 0; p < 3; p++)
      #pragma unroll
      for (int rf = 0; rf < 2; rf++)
        fa[p][rf] = *reinterpret_cast<const short8v*>(&lsI[p][wr * 32 + rf * 16 + lr][kb]);
    #pragma unroll
    for (int cf = 0; cf < 2; cf++) {
      int bcol = wc * 32 + cf * 16 + lr;
      short8v fb0 = *reinterpret_cast<const short8v*>(&lsJ[0][bcol][kb]);
      short8v fb1 = *reinterpret_cast<const short8v*>(&lsJ[1][bcol][kb]);
      short8v fb2 = *reinterpret_cast<const short8v*>(&lsJ[2][bcol][kb]);
      #pragma unroll
      for (int rf = 0; rf < 2; rf++) {
        f32x4 a = acc[rf][cf];
        a = __builtin_amdgcn_mfma_f32_16x16x32_bf16(fa[0][rf], fb0, a, 0, 0, 0);
        a = __builtin_amdgcn_mfma_f32_16x16x32_bf16(fa[0][rf], fb1, a, 0, 0, 0);
        a = __builtin_amdgcn_mfma_f32_16x16x32_bf16(fa[1][rf], fb0, a, 0, 0, 0);
        a = __builtin_amdgcn_mfma_f32_16x16x32_bf16(fa[1][rf], fb1, a, 0, 0, 0);
        a = __builtin_amdgcn_mfma_f32_16x16x32_bf16(fa[0][rf], fb2, a, 0, 0, 0);
        a = __builtin_amdgcn_mfma_f32_16x16x32_bf16(fa[2][rf], fb0, a, 0, 0, 0);
        acc[rf][cf] = a;
      }
    }
    __syncthreads();
  }
  size_t base = ((size_t)blockIdx.y * 15 + bx) * 4096;
  #pragma unroll
  for (int rf = 0; rf < 2; rf++)
    #pragma unroll
    for (int cf = 0; cf < 2; cf++) {
      int col = wc * 32 + cf * 16 + lr;
      #pragma unroll
      for (int r = 0; r < 4; r++) {
        int row = wr * 32 + rf * 16 + rbase + r;
        gpart[base + (size_t)row * 64 + col] = (double)acc[rf][cf][r];
      }
    }
}

// ---------------- 64x64 fp32 GEMM (vn path / head) ----------------
template<bool AFUSE, bool ORELU>
__global__ __launch_bounds__(256) void k_gemm(
    const float* __restrict__ A, const float* __restrict__ W,
    const float* __restrict__ bias, float* __restrict__ C,
    int N, int K, int M,
    const float* __restrict__ ascale, const float* __restrict__ ashift)
{
  __shared__ __align__(16) float As[16][72];
  __shared__ __align__(16) float Bs[16][72];
  int tid = threadIdx.x;
  int row0 = blockIdx.x * 64;
  int col0 = blockIdx.y * 64;
  int tx = tid & 15, ty = tid >> 4;
  bool kvec = ((K & 3) == 0);
  bool mvec = ((M & 3) == 0);
  float acc[4][4] = {};
  for (int k0 = 0; k0 < K; k0 += 16) {
    {
      int r = tid >> 2;
      int kq = (tid & 3) * 4;
      int gr = row0 + r;
      float a0 = 0.f, a1 = 0.f, a2 = 0.f, a3 = 0.f;
      if (gr < N) {
        const float* ap = A + (size_t)gr * K + k0 + kq;
        int k = k0 + kq;
        if (kvec && k + 3 < K) {
          float4 t = *reinterpret_cast<const float4*>(ap);
          a0 = t.x; a1 = t.y; a2 = t.z; a3 = t.w;
        } else {
          if (k + 0 < K) a0 = ap[0];
          if (k + 1 < K) a1 = ap[1];
          if (k + 2 < K) a2 = ap[2];
          if (k + 3 < K) a3 = ap[3];
        }
        if (AFUSE) {
          if (k + 0 < K) a0 = fmaxf(fmaf(a0, ascale[k + 0], ashift[k + 0]), 0.f);
          if (k + 1 < K) a1 = fmaxf(fmaf(a1, ascale[k + 1], ashift[k + 1]), 0.f);
          if (k + 2 < K) a2 = fmaxf(fmaf(a2, ascale[k + 2], ashift[k + 2]), 0.f);
          if (k + 3 < K) a3 = fmaxf(fmaf(a3, ascale[k + 3], ashift[k + 3]), 0.f);
        }
      }
      As[kq + 0][r] = a0; As[kq + 1][r] = a1; As[kq + 2][r] = a2; As[kq + 3][r] = a3;
    }
    {
      int kk = tid >> 4;
      int j = (tid & 15) * 4;
      int gk = k0 + kk;
      float4 bv = {0.f, 0.f, 0.f, 0.f};
      if (gk < K) {
        const float* wp = W + (size_t)gk * M + col0 + j;
        if (mvec && col0 + j + 3 < M) {
          bv = *reinterpret_cast<const float4*>(wp);
        } else {
          if (col0 + j + 0 < M) bv.x = wp[0];
          if (col0 + j + 1 < M) bv.y = wp[1];
          if (col0 + j + 2 < M) bv.z = wp[2];
          if (col0 + j + 3 < M) bv.w = wp[3];
        }
      }
      *reinterpret_cast<float4*>(&Bs[kk][j]) = bv;
    }
    __syncthreads();
    #pragma unroll
    for (int kk = 0; kk < 16; kk++) {
      float4 a4 = *reinterpret_cast<const float4*>(&As[kk][ty * 4]);
      float4 b4 = *reinterpret_cast<const float4*>(&Bs[kk][tx * 4]);
      float a[4] = {a4.x, a4.y, a4.z, a4.w};
      float b[4] = {b4.x, b4.y, b4.z, b4.w};
      #pragma unroll
      for (int u = 0; u < 4; u++)
        #pragma unroll
        for (int v = 0; v < 4; v++)
          acc[u][v] = fmaf(a[u], b[v], acc[u][v]);
    }
    __syncthreads();
  }
  float bv[4];
  #pragma unroll
  for (int v = 0; v < 4; v++) { int gc = col0 + tx * 4 + v; bv[v] = (gc < M) ? bias[gc] : 0.f; }
  #pragma unroll
  for (int u = 0; u < 4; u++) {
    int gr = row0 + ty * 4 + u;
    if (gr >= N) continue;
    int gc0 = col0 + tx * 4;
    float val[4];
    #pragma unroll
    for (int v = 0; v < 4; v++) {
      float x = acc[u][v] + bv[v];
      if (ORELU) x = fmaxf(x, 0.f);
      val[v] = x;
    }
    if (mvec && gc0 + 3 < M) {
      float4 o = {val[0], val[1], val[2], val[3]};
      *reinterpret_cast<float4*>(C + (size_t)gr * M + gc0) = o;
    } else {
      #pragma unroll
      for (int v = 0; v < 4; v++) {
        int gc = gc0 + v;
        if (gc < M) C[(size_t)gr * M + gc] = val[v];
      }
    }
  }
}

__global__ void k_gramfin(const double* __restrict__ gpart, double* __restrict__ G)
{
  int e = blockIdx.x * 256 + threadIdx.x;
  if (e >= 15 * 4096) return;
  int tile = e >> 12;
  int ii = (e >> 6) & 63, jj = e & 63;
  const int tit[15] = {0,0,0,0,0,1,1,1,1,2,2,2,3,3,4};
  const int tjt[15] = {0,1,2,3,4,1,2,3,4,2,3,4,3,4,4};
  int gi = tit[tile] * 64 + ii, gj = tjt[tile] * 64 + jj;
  if (gi >= EMBD || gj >= EMBD) return;
  double s = 0.0;
  for (int kb = 0; kb < GRAM_KB; kb++)
    s += gpart[((size_t)kb * 15 + tile) * 4096 + ii * 64 + jj];
  G[(size_t)gi * EMBD + gj] = s;
  G[(size_t)gj * EMBD + gi] = s;
}

__global__ void k_bn1gram(const double* __restrict__ G, const double* __restrict__ cbuf,
                          const float* __restrict__ W1, const float* __restrict__ b1,
                          const float* __restrict__ g, const float* __restrict__ b,
                          int n, float* __restrict__ sc, float* __restrict__ sh)
{
  int j = blockIdx.x;
  int t = threadIdx.x;
  __shared__ double ws[EMBD];
  __shared__ double red[256];
  for (int k = t; k < EMBD; k += 256) ws[k] = (double)W1[(size_t)k * 600 + j];
  __syncthreads();
  int i1 = 256 + t;
  double y0 = 0.0, y1 = 0.0;
  for (int k = 0; k < EMBD; k++) {
    double wk = ws[k];
    y0 += G[(size_t)k * EMBD + t] * wk;
    if (i1 < EMBD) y1 += G[(size_t)k * EMBD + i1] * wk;
  }
  double part = ws[t] * y0 + ((i1 < EMBD) ? ws[i1] * y1 : 0.0);
  double dpart = cbuf[t] * ws[t] + ((i1 < EMBD) ? cbuf[i1] * ws[i1] : 0.0);
  red[t] = part; __syncthreads();
  for (int w = 128; w > 0; w >>= 1) { if (t < w) red[t] += red[t + w]; __syncthreads(); }
  double Q = red[0]; __syncthreads();
  red[t] = dpart; __syncthreads();
  for (int w = 128; w > 0; w >>= 1) { if (t < w) red[t] += red[t + w]; __syncthreads(); }
  if (t == 0) {
    double d = red[0];
    double bj = (double)b1[j];
    double S = d + (double)n * bj;
    double Qf = Q + 2.0 * bj * d + (double)n * bj * bj;
    double m = S / n;
    double var = Qf / n - m * m;
    double inv = 1.0 / sqrt(var + 1e-5);
    double scv = (double)g[j] * inv;
    sc[j] = (float)scv;
    sh[j] = (float)((double)b[j] - m * scv);
  }
}

// ---------------- column stats ----------------
__global__ void k_colstats(const float* __restrict__ X, int n, int C,
                           double* __restrict__ psum, double* __restrict__ psq)
{
  int tid = threadIdx.x;
  int col = blockIdx.x * 64 + (tid & 63);
  int rl = tid >> 6;
  double s = 0.0, q = 0.0;
  if (col < C) {
    int stride = gridDim.y * 4;
    for (int r = blockIdx.y * 4 + rl; r < n; r += stride) {
      double x = (double)X[(size_t)r * C + col];
      s += x; q += x * x;
    }
  }
  __shared__ double ls[2][4][64];
  ls[0][rl][tid & 63] = s;
  ls[1][rl][tid & 63] = q;
  __syncthreads();
  if (rl == 0 && col < C) {
    int c = tid & 63;
    double S = ls[0][0][c] + ls[0][1][c] + ls[0][2][c] + ls[0][3][c];
    double Q = ls[1][0][c] + ls[1][1][c] + ls[1][2][c] + ls[1][3][c];
    psum[(size_t)blockIdx.y * C + col] = S;
    psq [(size_t)blockIdx.y * C + col] = Q;
  }
}

__global__ void k_redcol(const double* __restrict__ psum, int R, int C, double* __restrict__ cbuf)
{
  int c = blockIdx.x * blockDim.x + threadIdx.x;
  if (c >= C) return;
  double s = 0.0;
  for (int r = 0; r < R; r++) s += psum[(size_t)r * C + c];
  cbuf[c] = s;
}

__global__ void k_finstats(const double* __restrict__ psum, const double* __restrict__ psq,
                           int R, int M, int n,
                           const float* __restrict__ g, const float* __restrict__ b,
                           float* __restrict__ sc, float* __restrict__ sh)
{
  int j = blockIdx.x;
  int t = threadIdx.x;
  double s = 0.0, q = 0.0;
  for (int r = t; r < R; r += 256) { s += psum[(size_t)r * M + j]; q += psq[(size_t)r * M + j]; }
  __shared__ double ls[256], lq[256];
  ls[t] = s; lq[t] = q; __syncthreads();
  for (int w = 128; w > 0; w >>= 1) {
    if (t < w) { ls[t] += ls[t + w]; lq[t] += lq[t + w]; }
    __syncthreads();
  }
  if (t == 0) {
    double m = ls[0] / n;
    double v = lq[0] / n - m * m;
    double inv = 1.0 / sqrt(v + 1e-5);
    double scv = (double)g[j] * inv;
    sc[j] = (float)scv;
    sh[j] = (float)((double)b[j] - m * scv);
  }
}

// ---------------- vn / pool / sem ----------------
__global__ void k_vnseg(const float* __restrict__ hl, const int* __restrict__ off,
                        const float* __restrict__ vn, float* __restrict__ vtmp)
{
  int g = blockIdx.x;
  int c = threadIdx.x;
  if (c >= EMBD) return;
  int r0 = off[g], r1 = off[g + 1];
  float s = 0.f;
  for (int r = r0; r < r1; r++) s += hl[(size_t)r * EMBD + c];
  vtmp[(size_t)g * EMBD + c] = s + vn[(size_t)g * EMBD + c];
}

__global__ void k_vnfinal(const float* __restrict__ vnraw, const float* __restrict__ scale,
                          const float* __restrict__ shift, float* __restrict__ vn, int total)
{
  int i = blockIdx.x * blockDim.x + threadIdx.x;
  if (i >= total) return;
  int c = i % EMBD;
  vn[i] = fmaxf(fmaf(vnraw[i], scale[c], shift[c]), 0.f);
}

__global__ void k_pool(const float* __restrict__ t2, const int* __restrict__ off,
                       const float* __restrict__ scale, const float* __restrict__ shift,
                       float* __restrict__ hg)
{
  int g = blockIdx.x;
  int c = threadIdx.x;
  if (c >= EMBD) return;
  int r0 = off[g], r1 = off[g + 1];
  float s = 0.f;
  for (int r = r0; r < r1; r++) s += t2[(size_t)r * EMBD + c];
  int cnt = r1 - r0;
  float denom = (cnt > 0) ? (float)cnt : 1.f;
  hg[(size_t)g * EMBD + c] = (scale[c] * s + shift[c] * (float)cnt) / denom;
}

__global__ void k_sem(const float* __restrict__ logits, const float* __restrict__ gum,
                      const float* __restrict__ selW, const float* __restrict__ selb,
                      float* __restrict__ msgw)
{
  int idx = blockIdx.x * blockDim.x + threadIdx.x;
  if (idx >= GNUM * LSEM) return;
  int g = idx / LSEM, l = idx % LSEM;
  const float* lp = logits + (size_t)g * (LSEM * VSEM) + l * VSEM;
  const float* gp = gum + (size_t)g * (LSEM * VSEM) + l * VSEM;
  float best = -1e30f; int bi = 0;
  for (int v = 0; v < VSEM; v++) {
    float y = lp[v] + gp[v];
    if (y > best) { best = y; bi = v; }
  }
  float* o = msgw + (size_t)g * (3 * LSEM) + l * 3;
  o[0] = selW[bi * 3 + 0] + selb[0];
  o[1] = selW[bi * 3 + 1] + selb[1];
  o[2] = selW[bi * 3 + 2] + selb[2];
}

// ---------------- host ----------------
template<bool AFUSE, bool ORELU>
static void gemm(const float* A, const float* W, const float* b, float* C,
                 int n, int k, int m, const float* sc, const float* sh, hipStream_t st)
{
  dim3 grid((n + 63) / 64, (m + 63) / 64);
  k_gemm<AFUSE, ORELU><<<grid, 256, 0, st>>>(A, W, b, C, n, k, m, sc, sh);
}

extern "C" void kernel_launch(void* const* d_in, const int* in_sizes, int n_in,
                              void* d_out, int out_size, void* d_ws, size_t ws_size,
                              hipStream_t stream)
{
  const int*   x_idx     = (const int*)d_in[0];
  const int*   eidx      = (const int*)d_in[1];
  const int*   eattr     = (const int*)d_in[2];
  const int*   batch     = (const int*)d_in[3];
  const float* gumbel    = (const float*)d_in[4];
  const float* atom_emb  = (const float*)d_in[5];
  const float* bond_emb  = (const float*)d_in[6];
  const float* eps       = (const float*)d_in[7];
  const float* gin_W1    = (const float*)d_in[8];
  const float* gin_b1    = (const float*)d_in[9];
  const float* gin_bn1_g = (const float*)d_in[10];
  const float* gin_bn1_b = (const float*)d_in[11];
  const float* gin_W2    = (const float*)d_in[12];
  const float* gin_b2    = (const float*)d_in[13];
  const float* node_bn_g = (const float*)d_in[14];
  const float* node_bn_b = (const float*)d_in[15];
  const float* vn_W1     = (const float*)d_in[16];
  const float* vn_b1     = (const float*)d_in[17];
  const float* vn_bn1_g  = (const float*)d_in[18];
  const float* vn_bn1_b  = (const float*)d_in[19];
  const float* vn_W2     = (const float*)d_in[20];
  const float* vn_b2     = (const float*)d_in[21];
  const float* vn_bn2_g  = (const float*)d_in[22];
  const float* vn_bn2_b  = (const float*)d_in[23];
  const float* pre_W     = (const float*)d_in[24];
  const float* pre_b     = (const float*)d_in[25];
  const float* sel_W     = (const float*)d_in[26];
  const float* sel_b     = (const float*)d_in[27];
  const float* aft_W     = (const float*)d_in[28];
  const float* aft_b     = (const float*)d_in[29];
  const float* hW1       = (const float*)d_in[30];
  const float* hb1       = (const float*)d_in[31];
  const float* hW2       = (const float*)d_in[32];
  const float* hb2       = (const float*)d_in[33];
  const float* hW3       = (const float*)d_in[34];
  const float* hb3       = (const float*)d_in[35];

  const int N = in_sizes[0];
  const int E = in_sizes[2];
  const int RB = 128;
  float* out = (float*)d_out;
  (void)n_in;

  char* ws = (char*)d_ws;
  size_t pos = 0;
  auto alloc = [&](size_t bytes) -> char* {
    char* p = ws + pos;
    pos = (pos + bytes + 255) & ~(size_t)255;
    return p;
  };
  int*    off   = (int*)   alloc((GNUM + 1) * sizeof(int));
  float*  hbuf0 = (float*) alloc((size_t)N * EMBD * 4);
  float*  hbuf1 = (float*) alloc((size_t)N * EMBD * 4);
  double* psum  = (double*)alloc((size_t)RB2 * 300 * 8);   // also used as [128][600] (76800 <= 153600)
  double* psq   = (double*)alloc((size_t)RB2 * 300 * 8);
  float*  vn    = (float*) alloc((size_t)GNUM * EMBD * 4);
  float*  vtmp  = (float*) alloc((size_t)GNUM * EMBD * 4);
  float*  vnraw = (float*) alloc((size_t)GNUM * EMBD * 4);
  double* cbuf  = (double*)alloc(EMBD * 8);
  int*    off2  = (int*)   alloc((size_t)(N + 1) * 4);
  int*    eix   = (int*)   alloc((size_t)E * 4);
  short*  wsplit1 = (short*)alloc((size_t)600 * 320 * 3 * 2);
  short*  wsplit2 = (short*)alloc((size_t)300 * 608 * 3 * 2);
  float*  s1    = (float*) alloc(600 * 4);
  float*  sh1   = (float*) alloc(600 * 4);
  float*  s2    = (float*) alloc(EMBD * 4);
  float*  sh2   = (float*) alloc(EMBD * 4);
  float*  vs1   = (float*) alloc(600 * 4);
  float*  vsh1  = (float*) alloc(600 * 4);
  float*  vs2   = (float*) alloc(EMBD * 4);
  float*  vsh2  = (float*) alloc(EMBD * 4);

  const size_t gpartBytes = (size_t)GRAM_KB * 15 * 4096 * 8;
  const size_t gBytes     = (size_t)EMBD * EMBD * 8;
  const size_t csrScratch = (size_t)N * 4 * 3 + 4096;
  const long long CH_MIN  = 2048;
  size_t slack = 1u << 20;
  size_t region_need = gpartBytes + gBytes;
  if (region_need < csrScratch) region_need = csrScratch;
  size_t t1_min = (size_t)CH_MIN * 600 * 4;
  if (region_need < t1_min) region_need = t1_min;

  if (ws_size < pos + region_need + slack) {
    float v = 1000.f + (float)(ws_size >> 20);
    k_diag<<<(out_size + 255) / 256, 256, 0, stream>>>(out, out_size, v);
    return;
  }

  size_t regionBytes = ws_size - pos - slack;
  char* region = ws + pos;
  int* deg  = (int*)region;
  int* incl = (int*)(region + (size_t)N * 4);
  int* cur  = (int*)(region + (size_t)N * 8);
  int* part = (int*)(region + (size_t)N * 12);
  double* gpart = (double*)region;
  double* G     = (double*)(region + gpartBytes);
  float*  t1buf = (float*)region;
  int CH;
  {
    long long ch = (long long)(regionBytes / (600ull * 4ull));
    if (ch > 32768) ch = 32768;
    ch &= ~63LL;
    if (ch < CH_MIN) ch = CH_MIN;
    long long npad = ((long long)N + 63) & ~63LL;
    if (ch > npad && npad >= CH_MIN) ch = npad;
    CH = (int)ch;
  }
  float* v1 = t1buf;
  float* hg     = vnraw;
  float* logits = t1buf;
  float* msgw   = t1buf + (size_t)GNUM * EMBD;
  float* dis    = vtmp;
  float* o1     = vn;
  float* o2     = vn + (size_t)GNUM * 128;

  k_zero<<<(GNUM * EMBD + 255) / 256, 256, 0, stream>>>(vn, GNUM * EMBD);
  k_offsets<<<(GNUM + 1 + 255) / 256, 256, 0, stream>>>(batch, N, off);

  const int* esrc = eidx;
  const int* edst = eidx + E;

  // CSR build (once)
  {
    int NB = (N + 255) / 256;
    k_seti<<<(N + 255) / 256, 256, 0, stream>>>(deg, N, 0);
    k_deg<<<(E + 255) / 256, 256, 0, stream>>>(edst, E, deg);
    k_scan1<<<NB, 256, 0, stream>>>(deg, N, incl, part);
    k_scan2<<<1, 512, 0, stream>>>(part, NB);
    k_scan3<<<(N + 255) / 256, 256, 0, stream>>>(deg, incl, part, N, E, off2);
    k_copyi<<<(N + 255) / 256, 256, 0, stream>>>(off2, cur, N);
    k_fill<<<(E + 255) / 256, 256, 0, stream>>>(edst, E, cur, eix);
  }

  float* hb[2] = {hbuf0, hbuf1};

  for (int l = 0; l < NLAY; l++) {
    float* tac = hb[l & 1];
    float* hlb = hb[(l + 1) & 1];

    if (l == 0)
      k_hl<true><<<N, 320, 0, stream>>>(atom_emb, x_idx, nullptr, nullptr, batch, vn, eps, l, tac, hlb, N);
    else
      k_hl<false><<<N, 320, 0, stream>>>(nullptr, nullptr, s2, sh2, batch, vn, eps, l, tac, hlb, N);

    k_gather<<<(N + 3) / 4, 256, 0, stream>>>(off2, eix, esrc, eattr, hlb,
                                              bond_emb + (size_t)l * 5 * EMBD, tac, N);

    if (l < NLAY - 1)
      k_vnseg<<<GNUM, 320, 0, stream>>>(hlb, off, vn, vtmp);

    // BN1 stats via Gram identity (MFMA gram)
    k_colstats<<<dim3(5, RB), 256, 0, stream>>>(tac, N, EMBD, psum, psq);
    k_redcol<<<2, 256, 0, stream>>>(psum, RB, EMBD, cbuf);
    k_mgram<<<dim3(15, GRAM_KB), 256, 0, stream>>>(tac, N, gpart);
    k_gramfin<<<240, 256, 0, stream>>>(gpart, G);
    k_bn1gram<<<600, 256, 0, stream>>>(G, cbuf, gin_W1 + (size_t)l * EMBD * 600,
                                       gin_b1 + (size_t)l * 600,
                                       gin_bn1_g + (size_t)l * 600, gin_bn1_b + (size_t)l * 600,
                                       N, s1, sh1);

    // pre-split weights into bf16 planes
    k_splitW<<<(600 * 320 + 255) / 256, 256, 0, stream>>>(gin_W1 + (size_t)l * EMBD * 600, 300, 320, 600, wsplit1);
    k_splitW<<<(300 * 608 + 255) / 256, 256, 0, stream>>>(gin_W2 + (size_t)l * 600 * EMBD, 600, 608, 300, wsplit2);

    // zero node-BN partials (accumulated across chunks in GEMM2 epilogue)
    k_zero<<<(RB2 * 300 * 2 + 255) / 256, 256, 0, stream>>>((float*)psum, RB2 * 300 * 2);
    k_zero<<<(RB2 * 300 * 2 + 255) / 256, 256, 0, stream>>>((float*)psq, RB2 * 300 * 2);

    // chunked split-MFMA GEMM1 (CT=2) -> t1buf -> GEMM2 (CT=1, fused node-BN stats) -> h rows
    for (int r0 = 0; r0 < N; r0 += CH) {
      int nr = (N - r0 < CH) ? (N - r0) : CH;
      dim3 g1((nr + 63) / 64, 5);
      k_mgemm<2, false, false><<<g1, 256, 0, stream>>>(tac + (size_t)r0 * EMBD, wsplit1,
                                                       gin_b1 + (size_t)l * 600, t1buf,
                                                       nr, 300, 320, 600, nullptr, nullptr,
                                                       nullptr, nullptr);
      dim3 g2((nr + 63) / 64, 5);
      k_mgemm<1, true, true><<<g2, 256, 0, stream>>>(t1buf, wsplit2,
                                                     gin_b2 + (size_t)l * EMBD, hlb + (size_t)r0 * EMBD,
                                                     nr, 600, 608, 300, s1, sh1,
                                                     psum, psq);
    }
    k_finstats<<<EMBD, 256, 0, stream>>>(psum, psq, RB2, EMBD, N,
                                         node_bn_g + (size_t)l * EMBD, node_bn_b + (size_t)l * EMBD, s2, sh2);

    if (l < NLAY - 1) {
      gemm<false, false>(vtmp, vn_W1 + (size_t)l * EMBD * 600, vn_b1 + (size_t)l * 600, v1,
                         GNUM, EMBD, 600, nullptr, nullptr, stream);
      k_colstats<<<dim3(10, RB), 256, 0, stream>>>(v1, GNUM, 600, psum, psq);
      k_finstats<<<600, 256, 0, stream>>>(psum, psq, RB, 600, GNUM,
                                          vn_bn1_g + (size_t)l * 600, vn_bn1_b + (size_t)l * 600, vs1, vsh1);
      gemm<true, false>(v1, vn_W2 + (size_t)l * 600 * EMBD, vn_b2 + (size_t)l * EMBD, vnraw,
                        GNUM, 600, EMBD, vs1, vsh1, stream);
      k_colstats<<<dim3(5, RB), 256, 0, stream>>>(vnraw, GNUM, EMBD, psum, psq);
      k_finstats<<<EMBD, 256, 0, stream>>>(psum, psq, RB, EMBD, GNUM,
                                           vn_bn2_g + (size_t)l * EMBD, vn_bn2_b + (size_t)l * EMBD, vs2, vsh2);
      k_vnfinal<<<(GNUM * EMBD + 255) / 256, 256, 0, stream>>>(vnraw, vs2, vsh2, vn, GNUM * EMBD);
    }
  }

  float* lastH = hb[NLAY & 1];
  k_pool<<<GNUM, 320, 0, stream>>>(lastH, off, s2, sh2, hg);

  gemm<false, false>(hg, pre_W, pre_b, logits, GNUM, EMBD, LSEM * VSEM, nullptr, nullptr, stream);
  k_sem<<<(GNUM * LSEM + 255) / 256, 256, 0, stream>>>(logits, gumbel, sel_W, sel_b, msgw);
  gemm<false, false>(msgw, aft_W, aft_b, dis, GNUM, 3 * LSEM, EMBD, nullptr, nullptr, stream);
  gemm<false, true>(dis, hW1, hb1, o1, GNUM, EMBD, 128, nullptr, nullptr, stream);
  gemm<false, true>(o1, hW2, hb2, o2, GNUM, 128, 128, nullptr, nullptr, stream);
  gemm<false, false>(o2, hW3, hb3, out, GNUM, 128, 128, nullptr, nullptr, stream);
}

// Round 19
// 9802.543 us; speedup vs baseline: 1.0674x; 1.0674x over previous
//
#include <hip/hip_runtime.h>
#include <cstdint>

#define EMBD 300
#define GNUM 2048
#define LSEM 10
#define VSEM 30
#define NLAY 5
#define GRAM_KB 24

typedef __attribute__((ext_vector_type(8))) short short8v;
typedef __attribute__((ext_vector_type(4))) float f32x4;

// exact fp32 -> 3x bf16 split (integer RNE; weight pre-split)
__device__ __forceinline__ void split3(float x, short& h1, short& h2, short& h3) {
  unsigned u = __float_as_uint(x);
  unsigned uh = (u + 0x7FFFu + ((u >> 16) & 1u)) & 0xFFFF0000u;
  h1 = (short)(uh >> 16);
  float r = x - __uint_as_float(uh);
  unsigned v = __float_as_uint(r);
  unsigned vh = (v + 0x7FFFu + ((v >> 16) & 1u)) & 0xFFFF0000u;
  h2 = (short)(vh >> 16);
  float r2 = r - __uint_as_float(vh);
  unsigned w = __float_as_uint(r2);
  unsigned wh = (w + 0x7FFFu + ((w >> 16) & 1u)) & 0xFFFF0000u;
  h3 = (short)(wh >> 16);
}

// packed fp32x2 -> bf16x2 (1 HW instr)
__device__ __forceinline__ unsigned cvt_pk_bf16(float lo, float hi) {
  unsigned r;
  asm("v_cvt_pk_bf16_f32 %0, %1, %2" : "=v"(r) : "v"(lo), "v"(hi));
  return r;
}

// split a PAIR of fp32 into 3 packed-bf16 limbs (residuals exact)
__device__ __forceinline__ void split3_pair(float x0, float x1,
                                            unsigned& u1, unsigned& u2, unsigned& u3) {
  u1 = cvt_pk_bf16(x0, x1);
  float r0 = x0 - __uint_as_float(u1 << 16);
  float r1 = x1 - __uint_as_float(u1 & 0xFFFF0000u);
  u2 = cvt_pk_bf16(r0, r1);
  float s0 = r0 - __uint_as_float(u2 << 16);
  float s1 = r1 - __uint_as_float(u2 & 0xFFFF0000u);
  u3 = cvt_pk_bf16(s0, s1);
}

// ---------------- diagnostics / utility ----------------
__global__ void k_diag(float* __restrict__ p, int n, float v) {
  int i = blockIdx.x * blockDim.x + threadIdx.x;
  if (i < n) p[i] = v;
}

__global__ void k_zero(float* __restrict__ p, int n) {
  int i = blockIdx.x * blockDim.x + threadIdx.x;
  if (i < n) p[i] = 0.f;
}

__global__ void k_seti(int* __restrict__ p, int n, int v) {
  int i = blockIdx.x * blockDim.x + threadIdx.x;
  if (i < n) p[i] = v;
}

// offsets via binary search (batch is sorted)
__global__ void k_offsets(const int* __restrict__ batch, int N, int* __restrict__ off) {
  int g = blockIdx.x * blockDim.x + threadIdx.x;
  if (g > GNUM) return;
  int lo = 0, hi = N;
  while (lo < hi) { int mid = (lo + hi) >> 1; if (batch[mid] < g) lo = mid + 1; else hi = mid; }
  off[g] = lo;
}

// ---------------- CSR build ----------------
__global__ void k_deg(const int* __restrict__ dst, int E, int* __restrict__ deg) {
  int e = blockIdx.x * blockDim.x + threadIdx.x;
  if (e < E) atomicAdd(&deg[dst[e]], 1);
}

__global__ void k_scan1(const int* __restrict__ deg, int N,
                        int* __restrict__ incl, int* __restrict__ part) {
  __shared__ int s[256];
  int tid = threadIdx.x;
  int i = blockIdx.x * 256 + tid;
  int v = (i < N) ? deg[i] : 0;
  s[tid] = v; __syncthreads();
  for (int o = 1; o < 256; o <<= 1) {
    int t = (tid >= o) ? s[tid - o] : 0;
    __syncthreads();
    s[tid] += t;
    __syncthreads();
  }
  if (i < N) incl[i] = s[tid];
  if (tid == 255) part[blockIdx.x] = s[255];
}

__global__ void k_scan2(int* __restrict__ part, int nb) {
  __shared__ int s[512];
  int t = threadIdx.x;
  if (nb <= 512) {
    int v = (t < nb) ? part[t] : 0;
    s[t] = v; __syncthreads();
    for (int o = 1; o < 512; o <<= 1) {
      int u = (t >= o) ? s[t - o] : 0;
      __syncthreads();
      s[t] += u;
      __syncthreads();
    }
    if (t < nb) part[t] = s[t] - v;
  } else if (t == 0) {
    int run = 0;
    for (int i = 0; i < nb; i++) { int x = part[i]; part[i] = run; run += x; }
  }
}

__global__ void k_scan3(const int* __restrict__ deg, const int* __restrict__ incl,
                        const int* __restrict__ part, int N, int E, int* __restrict__ off2) {
  int i = blockIdx.x * blockDim.x + threadIdx.x;
  if (i < N) off2[i] = part[i >> 8] + incl[i] - deg[i];
  if (i == 0) off2[N] = E;
}

__global__ void k_copyi(const int* __restrict__ a, int* __restrict__ b, int n) {
  int i = blockIdx.x * blockDim.x + threadIdx.x;
  if (i < n) b[i] = a[i];
}

__global__ void k_fill(const int* __restrict__ dst, int E,
                       int* __restrict__ cur, int* __restrict__ eix) {
  int e = blockIdx.x * blockDim.x + threadIdx.x;
  if (e >= E) return;
  int p = atomicAdd(&cur[dst[e]], 1);
  eix[p] = e;
}

// ---------------- hl / tacc ----------------
template<bool FIRST>
__global__ void k_hl(const float* __restrict__ aemb, const int* __restrict__ x_idx,
                     const float* __restrict__ scale, const float* __restrict__ shift,
                     const int* __restrict__ batch, const float* __restrict__ vn,
                     const float* __restrict__ epsArr, int l,
                     float* pt, float* __restrict__ hl, int N)
{
  int i = blockIdx.x;
  int c = threadIdx.x;
  if (c >= EMBD) return;
  float x;
  if (FIRST) {
    x = aemb[(size_t)x_idx[i] * EMBD + c];
  } else {
    x = pt[(size_t)i * EMBD + c];
    x = fmaxf(fmaf(x, scale[c], shift[c]), 0.f);
  }
  float h = x + vn[(size_t)batch[i] * EMBD + c];
  hl[(size_t)i * EMBD + c] = h;
  pt[(size_t)i * EMBD + c] = (1.f + epsArr[l]) * h;
}

// ---------------- CSR gather (2-edge ILP) ----------------
__global__ void k_gather(const int* __restrict__ off2, const int* __restrict__ eix,
                         const int* __restrict__ src, const int* __restrict__ eattr,
                         const float* __restrict__ hl, const float* __restrict__ bond,
                         float* __restrict__ tacc, int N)
{
  int node = blockIdx.x * 4 + (threadIdx.x >> 6);
  int lane = threadIdx.x & 63;
  if (node >= N) return;
  int p0 = off2[node], p1 = off2[node + 1];
  if (p0 == p1) return;
  float acc[5] = {0.f, 0.f, 0.f, 0.f, 0.f};
  int p = p0;
  for (; p + 1 < p1; p += 2) {
    int eA = eix[p], eB = eix[p + 1];
    int sA = src[eA], aA = eattr[eA];
    int sB = src[eB], aB = eattr[eB];
    const float* hA = hl + (size_t)sA * EMBD;
    const float* bA = bond + (size_t)aA * EMBD;
    const float* hB = hl + (size_t)sB * EMBD;
    const float* bB = bond + (size_t)aB * EMBD;
    #pragma unroll
    for (int q = 0; q < 5; q++) {
      int c = lane + q * 64;
      if (c < EMBD) {
        acc[q] += fmaxf(hA[c] + bA[c], 0.f);
        acc[q] += fmaxf(hB[c] + bB[c], 0.f);
      }
    }
  }
  if (p < p1) {
    int e = eix[p];
    int s = src[e], a = eattr[e];
    const float* hr = hl + (size_t)s * EMBD;
    const float* br = bond + (size_t)a * EMBD;
    #pragma unroll
    for (int q = 0; q < 5; q++) {
      int c = lane + q * 64;
      if (c < EMBD) acc[q] += fmaxf(hr[c] + br[c], 0.f);
    }
  }
  float* tr = tacc + (size_t)node * EMBD;
  #pragma unroll
  for (int q = 0; q < 5; q++) {
    int c = lane + q * 64;
    if (c < EMBD) tr[c] += acc[q];
  }
}

// ---------------- W split: [K][M] fp32 -> 3 bf16 planes [M][Kpad] ----------------
__global__ void k_splitW(const float* __restrict__ W, int K, int Kpad, int M,
                         short* __restrict__ planes)
{
  int idx = blockIdx.x * 256 + threadIdx.x;
  if (idx >= M * Kpad) return;
  int m = idx / Kpad, k = idx - m * Kpad;
  float x = (k < K) ? W[(size_t)k * M + m] : 0.f;
  short h1, h2, h3; split3(x, h1, h2, h3);
  size_t ps = (size_t)M * Kpad;
  planes[idx] = h1; planes[ps + idx] = h2; planes[2 * ps + idx] = h3;
}

// ---------------- split-bf16 MFMA GEMM, CT*64-col tiles (proven) ----------------
template<int CT, bool AFUSE>
__global__ __launch_bounds__(256) void k_mgemm(
    const float* __restrict__ A, const short* __restrict__ Wp,
    const float* __restrict__ bias, float* __restrict__ C,
    int n, int K, int Kpad, int M,
    const float* __restrict__ ascale, const float* __restrict__ ashift)
{
  __shared__ __align__(16) short lsA[3][64][40];
  __shared__ __align__(16) short lsB[3][CT * 64][40];
  int tid = threadIdx.x;
  int row0 = blockIdx.x * 64;
  int col0 = blockIdx.y * (CT * 64);
  int l = tid & 63, wid = tid >> 6;
  int wr = wid >> 1, wc = wid & 1;
  int lr = l & 15, kb = (l >> 4) * 8, rbase = (l >> 4) * 4;
  int sar = tid >> 2;
  int sak = (tid & 3) * 8;
  size_t planeSz = (size_t)M * Kpad;

  f32x4 acc[2][CT * 2];
  #pragma unroll
  for (int i = 0; i < 2; i++)
    #pragma unroll
    for (int j = 0; j < CT * 2; j++) acc[i][j] = (f32x4){0.f, 0.f, 0.f, 0.f};

  for (int k0 = 0; k0 < Kpad; k0 += 32) {
    {
      int gr = row0 + sar;
      int kbase = k0 + sak;
      float x[8];
      if (gr < n && kbase + 7 < K) {
        const float* ap = A + (size_t)gr * K + kbase;
        float4 u0 = *reinterpret_cast<const float4*>(ap);
        float4 u1 = *reinterpret_cast<const float4*>(ap + 4);
        x[0] = u0.x; x[1] = u0.y; x[2] = u0.z; x[3] = u0.w;
        x[4] = u1.x; x[5] = u1.y; x[6] = u1.z; x[7] = u1.w;
        if (AFUSE) {
          float4 sc0 = *reinterpret_cast<const float4*>(ascale + kbase);
          float4 sc1 = *reinterpret_cast<const float4*>(ascale + kbase + 4);
          float4 sf0 = *reinterpret_cast<const float4*>(ashift + kbase);
          float4 sf1 = *reinterpret_cast<const float4*>(ashift + kbase + 4);
          x[0] = fmaxf(fmaf(x[0], sc0.x, sf0.x), 0.f);
          x[1] = fmaxf(fmaf(x[1], sc0.y, sf0.y), 0.f);
          x[2] = fmaxf(fmaf(x[2], sc0.z, sf0.z), 0.f);
          x[3] = fmaxf(fmaf(x[3], sc0.w, sf0.w), 0.f);
          x[4] = fmaxf(fmaf(x[4], sc1.x, sf1.x), 0.f);
          x[5] = fmaxf(fmaf(x[5], sc1.y, sf1.y), 0.f);
          x[6] = fmaxf(fmaf(x[6], sc1.z, sf1.z), 0.f);
          x[7] = fmaxf(fmaf(x[7], sc1.w, sf1.w), 0.f);
        }
      } else {
        #pragma unroll
        for (int j = 0; j < 8; j++) {
          int k = kbase + j;
          float v = 0.f;
          if (gr < n && k < K) {
            v = A[(size_t)gr * K + k];
            if (AFUSE) v = fmaxf(fmaf(v, ascale[k], ashift[k]), 0.f);
          }
          x[j] = v;
        }
      }
      uint4 q1, q2, q3;
      unsigned* p1 = (unsigned*)&q1; unsigned* p2 = (unsigned*)&q2; unsigned* p3 = (unsigned*)&q3;
      #pragma unroll
      for (int j = 0; j < 4; j++) split3_pair(x[2 * j], x[2 * j + 1], p1[j], p2[j], p3[j]);
      *reinterpret_cast<uint4*>(&lsA[0][sar][sak]) = q1;
      *reinterpret_cast<uint4*>(&lsA[1][sar][sak]) = q2;
      *reinterpret_cast<uint4*>(&lsA[2][sar][sak]) = q3;
    }
    if constexpr (CT == 2) {
      int sbc = tid >> 1;
      int sbk = (tid & 1) * 16;
      int gc = col0 + sbc;
      #pragma unroll
      for (int p = 0; p < 3; p++) {
        short8v v0, v1;
        if (gc < M) {
          const short* bp = Wp + (size_t)p * planeSz + (size_t)gc * Kpad + k0 + sbk;
          v0 = *reinterpret_cast<const short8v*>(bp);
          v1 = *reinterpret_cast<const short8v*>(bp + 8);
        } else {
          #pragma unroll
          for (int j = 0; j < 8; j++) { v0[j] = 0; v1[j] = 0; }
        }
        *reinterpret_cast<short8v*>(&lsB[p][sbc][sbk]) = v0;
        *reinterpret_cast<short8v*>(&lsB[p][sbc][sbk + 8]) = v1;
      }
    } else {
      int sbc = tid >> 2;
      int sbk = (tid & 3) * 8;
      int gc = col0 + sbc;
      #pragma unroll
      for (int p = 0; p < 3; p++) {
        short8v v0;
        if (gc < M) {
          const short* bp = Wp + (size_t)p * planeSz + (size_t)gc * Kpad + k0 + sbk;
          v0 = *reinterpret_cast<const short8v*>(bp);
        } else {
          #pragma unroll
          for (int j = 0; j < 8; j++) v0[j] = 0;
        }
        *reinterpret_cast<short8v*>(&lsB[p][sbc][sbk]) = v0;
      }
    }
    __syncthreads();
    short8v fa[3][2];
    #pragma unroll
    for (int p = 0; p < 3; p++)
      #pragma unroll
      for (int rf = 0; rf < 2; rf++)
        fa[p][rf] = *reinterpret_cast<const short8v*>(&lsA[p][wr * 32 + rf * 16 + lr][kb]);
    #pragma unroll
    for (int cf = 0; cf < CT * 2; cf++) {
      int bcol = wc * (CT * 32) + cf * 16 + lr;
      short8v fb0 = *reinterpret_cast<const short8v*>(&lsB[0][bcol][kb]);
      short8v fb1 = *reinterpret_cast<const short8v*>(&lsB[1][bcol][kb]);
      short8v fb2 = *reinterpret_cast<const short8v*>(&lsB[2][bcol][kb]);
      #pragma unroll
      for (int rf = 0; rf < 2; rf++) {
        f32x4 a = acc[rf][cf];
        a = __builtin_amdgcn_mfma_f32_16x16x32_bf16(fa[0][rf], fb0, a, 0, 0, 0);
        a = __builtin_amdgcn_mfma_f32_16x16x32_bf16(fa[0][rf], fb1, a, 0, 0, 0);
        a = __builtin_amdgcn_mfma_f32_16x16x32_bf16(fa[1][rf], fb0, a, 0, 0, 0);
        a = __builtin_amdgcn_mfma_f32_16x16x32_bf16(fa[1][rf], fb1, a, 0, 0, 0);
        a = __builtin_amdgcn_mfma_f32_16x16x32_bf16(fa[0][rf], fb2, a, 0, 0, 0);
        a = __builtin_amdgcn_mfma_f32_16x16x32_bf16(fa[2][rf], fb0, a, 0, 0, 0);
        acc[rf][cf] = a;
      }
    }
    __syncthreads();
  }
  #pragma unroll
  for (int rf = 0; rf < 2; rf++) {
    #pragma unroll
    for (int cf = 0; cf < CT * 2; cf++) {
      int col = col0 + wc * (CT * 32) + cf * 16 + lr;
      if (col >= M) continue;
      float bv = bias[col];
      #pragma unroll
      for (int r = 0; r < 4; r++) {
        int row = row0 + wr * 32 + rf * 16 + rbase + r;
        if (row < n) C[(size_t)row * M + col] = acc[rf][cf][r] + bv;
      }
    }
  }
}

// ---------------- MFMA Gram ----------------
__global__ __launch_bounds__(256) void k_mgram(const float* __restrict__ A, int N,
                                               double* __restrict__ gpart)
{
  int bx = blockIdx.x;
  int ti = 0;
  {
    const int o1 = 5, o2 = 9, o3 = 12, o4 = 14;
    if (bx >= o1) ti = 1;
    if (bx >= o2) ti = 2;
    if (bx >= o3) ti = 3;
    if (bx >= o4) ti = 4;
  }
  const int offs[5] = {0, 5, 9, 12, 14};
  int tj = ti + (bx - offs[ti]);
  int I = ti * 64, J = tj * 64;
  __shared__ __align__(16) short lsI[3][64][40];
  __shared__ __align__(16) short lsJ[3][64][40];
  int tid = threadIdx.x;
  int l = tid & 63, wid = tid >> 6;
  int wr = wid >> 1, wc = wid & 1;
  int lr = l & 15, kb = (l >> 4) * 8, rbase = (l >> 4) * 4;
  int sr = tid & 31;
  int sc0 = (tid >> 5) * 8;

  f32x4 acc[2][2];
  #pragma unroll
  for (int i = 0; i < 2; i++)
    #pragma unroll
    for (int j = 0; j < 2; j++) acc[i][j] = (f32x4){0.f, 0.f, 0.f, 0.f};

  for (int r0 = blockIdx.y * 32; r0 < N; r0 += gridDim.y * 32) {
    int gr = r0 + sr;
    float xi[8], xj[8];
    {
      int ci = I + sc0;
      if (gr < N && ci + 7 < EMBD) {
        const float* ap = A + (size_t)gr * EMBD + ci;
        float4 u0 = *reinterpret_cast<const float4*>(ap);
        float4 u1 = *reinterpret_cast<const float4*>(ap + 4);
        xi[0] = u0.x; xi[1] = u0.y; xi[2] = u0.z; xi[3] = u0.w;
        xi[4] = u1.x; xi[5] = u1.y; xi[6] = u1.z; xi[7] = u1.w;
      } else {
        #pragma unroll
        for (int j = 0; j < 8; j++) {
          int c = ci + j;
          xi[j] = (gr < N && c < EMBD) ? A[(size_t)gr * EMBD + c] : 0.f;
        }
      }
      int cj = J + sc0;
      if (gr < N && cj + 7 < EMBD) {
        const float* ap = A + (size_t)gr * EMBD + cj;
        float4 u0 = *reinterpret_cast<const float4*>(ap);
        float4 u1 = *reinterpret_cast<const float4*>(ap + 4);
        xj[0] = u0.x; xj[1] = u0.y; xj[2] = u0.z; xj[3] = u0.w;
        xj[4] = u1.x; xj[5] = u1.y; xj[6] = u1.z; xj[7] = u1.w;
      } else {
        #pragma unroll
        for (int j = 0; j < 8; j++) {
          int c = cj + j;
          xj[j] = (gr < N && c < EMBD) ? A[(size_t)gr * EMBD + c] : 0.f;
        }
      }
    }
    #pragma unroll
    for (int j = 0; j < 8; j++) {
      short a1, a2, a3; split3(xi[j], a1, a2, a3);
      lsI[0][sc0 + j][sr] = a1; lsI[1][sc0 + j][sr] = a2; lsI[2][sc0 + j][sr] = a3;
      short b1, b2, b3; split3(xj[j], b1, b2, b3);
      lsJ[0][sc0 + j][sr] = b1; lsJ[1][sc0 + j][sr] = b2; lsJ[2][sc0 + j][sr] = b3;
    }
    __syncthreads();
    short8v fa[3][2];
    #pragma unroll
    for (int p = 0; p < 3; p++)
      #pragma unroll
      for (int rf = 0; rf < 2; rf++)
        fa[p][rf] = *reinterpret_cast<const short8v*>(&lsI[p][wr * 32 + rf * 16 + lr][kb]);
    #pragma unroll
    for (int cf = 0; cf < 2; cf++) {
      int bcol = wc * 32 + cf * 16 + lr;
      short8v fb0 = *reinterpret_cast<const short8v*>(&lsJ[0][bcol][kb]);
      short8v fb1 = *reinterpret_cast<const short8v*>(&lsJ[1][bcol][kb]);
      short8v fb2 = *reinterpret_cast<const short8v*>(&lsJ[2][bcol][kb]);
      #pragma unroll
      for (int rf = 0; rf < 2; rf++) {
        f32x4 a = acc[rf][cf];
        a = __builtin_amdgcn_mfma_f32_16x16x32_bf16(fa[0][rf], fb0, a, 0, 0, 0);
        a = __builtin_amdgcn_mfma_f32_16x16x32_bf16(fa[0][rf], fb1, a, 0, 0, 0);
        a = __builtin_amdgcn_mfma_f32_16x16x32_bf16(fa[1][rf], fb0, a, 0, 0, 0);
        a = __builtin_amdgcn_mfma_f32_16x16x32_bf16(fa[1][rf], fb1, a, 0, 0, 0);
        a = __builtin_amdgcn_mfma_f32_16x16x32_bf16(fa[0][rf], fb2, a, 0, 0, 0);
        a = __builtin_amdgcn_mfma_f32_16x16x32_bf16(fa[2][rf], fb0, a, 0, 0, 0);
        acc[rf][cf] = a;
      }
    }
    __syncthreads();
  }
  size_t base = ((size_t)blockIdx.y * 15 + bx) * 4096;
  #pragma unroll
  for (int rf = 0; rf < 2; rf++)
    #pragma unroll
    for (int cf = 0; cf < 2; cf++) {
      int col = wc * 32 + cf * 16 + lr;
      #pragma unroll
      for (int r = 0; r < 4; r++) {
        int row = wr * 32 + rf * 16 + rbase + r;
        gpart[base + (size_t)row * 64 + col] = (double)acc[rf][cf][r];
      }
    }
}

// ---------------- 64x64 fp32 GEMM (vn path / head) ----------------
template<bool AFUSE, bool ORELU>
__global__ __launch_bounds__(256) void k_gemm(
    const float* __restrict__ A, const float* __restrict__ W,
    const float* __restrict__ bias, float* __restrict__ C,
    int N, int K, int M,
    const float* __restrict__ ascale, const float* __restrict__ ashift)
{
  __shared__ __align__(16) float As[16][72];
  __shared__ __align__(16) float Bs[16][72];
  int tid = threadIdx.x;
  int row0 = blockIdx.x * 64;
  int col0 = blockIdx.y * 64;
  int tx = tid & 15, ty = tid >> 4;
  bool kvec = ((K & 3) == 0);
  bool mvec = ((M & 3) == 0);
  float acc[4][4] = {};
  for (int k0 = 0; k0 < K; k0 += 16) {
    {
      int r = tid >> 2;
      int kq = (tid & 3) * 4;
      int gr = row0 + r;
      float a0 = 0.f, a1 = 0.f, a2 = 0.f, a3 = 0.f;
      if (gr < N) {
        const float* ap = A + (size_t)gr * K + k0 + kq;
        int k = k0 + kq;
        if (kvec && k + 3 < K) {
          float4 t = *reinterpret_cast<const float4*>(ap);
          a0 = t.x; a1 = t.y; a2 = t.z; a3 = t.w;
        } else {
          if (k + 0 < K) a0 = ap[0];
          if (k + 1 < K) a1 = ap[1];
          if (k + 2 < K) a2 = ap[2];
          if (k + 3 < K) a3 = ap[3];
        }
        if (AFUSE) {
          if (k + 0 < K) a0 = fmaxf(fmaf(a0, ascale[k + 0], ashift[k + 0]), 0.f);
          if (k + 1 < K) a1 = fmaxf(fmaf(a1, ascale[k + 1], ashift[k + 1]), 0.f);
          if (k + 2 < K) a2 = fmaxf(fmaf(a2, ascale[k + 2], ashift[k + 2]), 0.f);
          if (k + 3 < K) a3 = fmaxf(fmaf(a3, ascale[k + 3], ashift[k + 3]), 0.f);
        }
      }
      As[kq + 0][r] = a0; As[kq + 1][r] = a1; As[kq + 2][r] = a2; As[kq + 3][r] = a3;
    }
    {
      int kk = tid >> 4;
      int j = (tid & 15) * 4;
      int gk = k0 + kk;
      float4 bv = {0.f, 0.f, 0.f, 0.f};
      if (gk < K) {
        const float* wp = W + (size_t)gk * M + col0 + j;
        if (mvec && col0 + j + 3 < M) {
          bv = *reinterpret_cast<const float4*>(wp);
        } else {
          if (col0 + j + 0 < M) bv.x = wp[0];
          if (col0 + j + 1 < M) bv.y = wp[1];
          if (col0 + j + 2 < M) bv.z = wp[2];
          if (col0 + j + 3 < M) bv.w = wp[3];
        }
      }
      *reinterpret_cast<float4*>(&Bs[kk][j]) = bv;
    }
    __syncthreads();
    #pragma unroll
    for (int kk = 0; kk < 16; kk++) {
      float4 a4 = *reinterpret_cast<const float4*>(&As[kk][ty * 4]);
      float4 b4 = *reinterpret_cast<const float4*>(&Bs[kk][tx * 4]);
      float a[4] = {a4.x, a4.y, a4.z, a4.w};
      float b[4] = {b4.x, b4.y, b4.z, b4.w};
      #pragma unroll
      for (int u = 0; u < 4; u++)
        #pragma unroll
        for (int v = 0; v < 4; v++)
          acc[u][v] = fmaf(a[u], b[v], acc[u][v]);
    }
    __syncthreads();
  }
  float bv[4];
  #pragma unroll
  for (int v = 0; v < 4; v++) { int gc = col0 + tx * 4 + v; bv[v] = (gc < M) ? bias[gc] : 0.f; }
  #pragma unroll
  for (int u = 0; u < 4; u++) {
    int gr = row0 + ty * 4 + u;
    if (gr >= N) continue;
    int gc0 = col0 + tx * 4;
    float val[4];
    #pragma unroll
    for (int v = 0; v < 4; v++) {
      float x = acc[u][v] + bv[v];
      if (ORELU) x = fmaxf(x, 0.f);
      val[v] = x;
    }
    if (mvec && gc0 + 3 < M) {
      float4 o = {val[0], val[1], val[2], val[3]};
      *reinterpret_cast<float4*>(C + (size_t)gr * M + gc0) = o;
    } else {
      #pragma unroll
      for (int v = 0; v < 4; v++) {
        int gc = gc0 + v;
        if (gc < M) C[(size_t)gr * M + gc] = val[v];
      }
    }
  }
}

__global__ void k_gramfin(const double* __restrict__ gpart, double* __restrict__ G)
{
  int e = blockIdx.x * 256 + threadIdx.x;
  if (e >= 15 * 4096) return;
  int tile = e >> 12;
  int ii = (e >> 6) & 63, jj = e & 63;
  const int tit[15] = {0,0,0,0,0,1,1,1,1,2,2,2,3,3,4};
  const int tjt[15] = {0,1,2,3,4,1,2,3,4,2,3,4,3,4,4};
  int gi = tit[tile] * 64 + ii, gj = tjt[tile] * 64 + jj;
  if (gi >= EMBD || gj >= EMBD) return;
  double s = 0.0;
  for (int kb = 0; kb < GRAM_KB; kb++)
    s += gpart[((size_t)kb * 15 + tile) * 4096 + ii * 64 + jj];
  G[(size_t)gi * EMBD + gj] = s;
  G[(size_t)gj * EMBD + gi] = s;
}

__global__ void k_bn1gram(const double* __restrict__ G, const double* __restrict__ cbuf,
                          const float* __restrict__ W1, const float* __restrict__ b1,
                          const float* __restrict__ g, const float* __restrict__ b,
                          int n, float* __restrict__ sc, float* __restrict__ sh)
{
  int j = blockIdx.x;
  int t = threadIdx.x;
  __shared__ double ws[EMBD];
  __shared__ double red[256];
  for (int k = t; k < EMBD; k += 256) ws[k] = (double)W1[(size_t)k * 600 + j];
  __syncthreads();
  int i1 = 256 + t;
  double y0 = 0.0, y1 = 0.0;
  for (int k = 0; k < EMBD; k++) {
    double wk = ws[k];
    y0 += G[(size_t)k * EMBD + t] * wk;
    if (i1 < EMBD) y1 += G[(size_t)k * EMBD + i1] * wk;
  }
  double part = ws[t] * y0 + ((i1 < EMBD) ? ws[i1] * y1 : 0.0);
  double dpart = cbuf[t] * ws[t] + ((i1 < EMBD) ? cbuf[i1] * ws[i1] : 0.0);
  red[t] = part; __syncthreads();
  for (int w = 128; w > 0; w >>= 1) { if (t < w) red[t] += red[t + w]; __syncthreads(); }
  double Q = red[0]; __syncthreads();
  red[t] = dpart; __syncthreads();
  for (int w = 128; w > 0; w >>= 1) { if (t < w) red[t] += red[t + w]; __syncthreads(); }
  if (t == 0) {
    double d = red[0];
    double bj = (double)b1[j];
    double S = d + (double)n * bj;
    double Qf = Q + 2.0 * bj * d + (double)n * bj * bj;
    double m = S / n;
    double var = Qf / n - m * m;
    double inv = 1.0 / sqrt(var + 1e-5);
    double scv = (double)g[j] * inv;
    sc[j] = (float)scv;
    sh[j] = (float)((double)b[j] - m * scv);
  }
}

// ---------------- column stats ----------------
__global__ void k_colstats(const float* __restrict__ X, int n, int C,
                           double* __restrict__ psum, double* __restrict__ psq)
{
  int tid = threadIdx.x;
  int col = blockIdx.x * 64 + (tid & 63);
  int rl = tid >> 6;
  double s = 0.0, q = 0.0;
  if (col < C) {
    int stride = gridDim.y * 4;
    for (int r = blockIdx.y * 4 + rl; r < n; r += stride) {
      double x = (double)X[(size_t)r * C + col];
      s += x; q += x * x;
    }
  }
  __shared__ double ls[2][4][64];
  ls[0][rl][tid & 63] = s;
  ls[1][rl][tid & 63] = q;
  __syncthreads();
  if (rl == 0 && col < C) {
    int c = tid & 63;
    double S = ls[0][0][c] + ls[0][1][c] + ls[0][2][c] + ls[0][3][c];
    double Q = ls[1][0][c] + ls[1][1][c] + ls[1][2][c] + ls[1][3][c];
    psum[(size_t)blockIdx.y * C + col] = S;
    psq [(size_t)blockIdx.y * C + col] = Q;
  }
}

__global__ void k_redcol(const double* __restrict__ psum, int R, int C, double* __restrict__ cbuf)
{
  int c = blockIdx.x * blockDim.x + threadIdx.x;
  if (c >= C) return;
  double s = 0.0;
  for (int r = 0; r < R; r++) s += psum[(size_t)r * C + c];
  cbuf[c] = s;
}

__global__ void k_finstats(const double* __restrict__ psum, const double* __restrict__ psq,
                           int R, int M, int n,
                           const float* __restrict__ g, const float* __restrict__ b,
                           float* __restrict__ sc, float* __restrict__ sh)
{
  int j = blockIdx.x;
  int t = threadIdx.x;
  double s = 0.0, q = 0.0;
  for (int r = t; r < R; r += 256) { s += psum[(size_t)r * M + j]; q += psq[(size_t)r * M + j]; }
  __shared__ double ls[256], lq[256];
  ls[t] = s; lq[t] = q; __syncthreads();
  for (int w = 128; w > 0; w >>= 1) {
    if (t < w) { ls[t] += ls[t + w]; lq[t] += lq[t + w]; }
    __syncthreads();
  }
  if (t == 0) {
    double m = ls[0] / n;
    double v = lq[0] / n - m * m;
    double inv = 1.0 / sqrt(v + 1e-5);
    double scv = (double)g[j] * inv;
    sc[j] = (float)scv;
    sh[j] = (float)((double)b[j] - m * scv);
  }
}

// ---------------- vn / pool / sem ----------------
__global__ void k_vnseg(const float* __restrict__ hl, const int* __restrict__ off,
                        const float* __restrict__ vn, float* __restrict__ vtmp)
{
  int g = blockIdx.x;
  int c = threadIdx.x;
  if (c >= EMBD) return;
  int r0 = off[g], r1 = off[g + 1];
  float s = 0.f;
  for (int r = r0; r < r1; r++) s += hl[(size_t)r * EMBD + c];
  vtmp[(size_t)g * EMBD + c] = s + vn[(size_t)g * EMBD + c];
}

__global__ void k_vnfinal(const float* __restrict__ vnraw, const float* __restrict__ scale,
                          const float* __restrict__ shift, float* __restrict__ vn, int total)
{
  int i = blockIdx.x * blockDim.x + threadIdx.x;
  if (i >= total) return;
  int c = i % EMBD;
  vn[i] = fmaxf(fmaf(vnraw[i], scale[c], shift[c]), 0.f);
}

__global__ void k_pool(const float* __restrict__ t2, const int* __restrict__ off,
                       const float* __restrict__ scale, const float* __restrict__ shift,
                       float* __restrict__ hg)
{
  int g = blockIdx.x;
  int c = threadIdx.x;
  if (c >= EMBD) return;
  int r0 = off[g], r1 = off[g + 1];
  float s = 0.f;
  for (int r = r0; r < r1; r++) s += t2[(size_t)r * EMBD + c];
  int cnt = r1 - r0;
  float denom = (cnt > 0) ? (float)cnt : 1.f;
  hg[(size_t)g * EMBD + c] = (scale[c] * s + shift[c] * (float)cnt) / denom;
}

__global__ void k_sem(const float* __restrict__ logits, const float* __restrict__ gum,
                      const float* __restrict__ selW, const float* __restrict__ selb,
                      float* __restrict__ msgw)
{
  int idx = blockIdx.x * blockDim.x + threadIdx.x;
  if (idx >= GNUM * LSEM) return;
  int g = idx / LSEM, l = idx % LSEM;
  const float* lp = logits + (size_t)g * (LSEM * VSEM) + l * VSEM;
  const float* gp = gum + (size_t)g * (LSEM * VSEM) + l * VSEM;
  float best = -1e30f; int bi = 0;
  for (int v = 0; v < VSEM; v++) {
    float y = lp[v] + gp[v];
    if (y > best) { best = y; bi = v; }
  }
  float* o = msgw + (size_t)g * (3 * LSEM) + l * 3;
  o[0] = selW[bi * 3 + 0] + selb[0];
  o[1] = selW[bi * 3 + 1] + selb[1];
  o[2] = selW[bi * 3 + 2] + selb[2];
}

// ---------------- host ----------------
template<bool AFUSE, bool ORELU>
static void gemm(const float* A, const float* W, const float* b, float* C,
                 int n, int k, int m, const float* sc, const float* sh, hipStream_t st)
{
  dim3 grid((n + 63) / 64, (m + 63) / 64);
  k_gemm<AFUSE, ORELU><<<grid, 256, 0, st>>>(A, W, b, C, n, k, m, sc, sh);
}

extern "C" void kernel_launch(void* const* d_in, const int* in_sizes, int n_in,
                              void* d_out, int out_size, void* d_ws, size_t ws_size,
                              hipStream_t stream)
{
  const int*   x_idx     = (const int*)d_in[0];
  const int*   eidx      = (const int*)d_in[1];
  const int*   eattr     = (const int*)d_in[2];
  const int*   batch     = (const int*)d_in[3];
  const float* gumbel    = (const float*)d_in[4];
  const float* atom_emb  = (const float*)d_in[5];
  const float* bond_emb  = (const float*)d_in[6];
  const float* eps       = (const float*)d_in[7];
  const float* gin_W1    = (const float*)d_in[8];
  const float* gin_b1    = (const float*)d_in[9];
  const float* gin_bn1_g = (const float*)d_in[10];
  const float* gin_bn1_b = (const float*)d_in[11];
  const float* gin_W2    = (const float*)d_in[12];
  const float* gin_b2    = (const float*)d_in[13];
  const float* node_bn_g = (const float*)d_in[14];
  const float* node_bn_b = (const float*)d_in[15];
  const float* vn_W1     = (const float*)d_in[16];
  const float* vn_b1     = (const float*)d_in[17];
  const float* vn_bn1_g  = (const float*)d_in[18];
  const float* vn_bn1_b  = (const float*)d_in[19];
  const float* vn_W2     = (const float*)d_in[20];
  const float* vn_b2     = (const float*)d_in[21];
  const float* vn_bn2_g  = (const float*)d_in[22];
  const float* vn_bn2_b  = (const float*)d_in[23];
  const float* pre_W     = (const float*)d_in[24];
  const float* pre_b     = (const float*)d_in[25];
  const float* sel_W     = (const float*)d_in[26];
  const float* sel_b     = (const float*)d_in[27];
  const float* aft_W     = (const float*)d_in[28];
  const float* aft_b     = (const float*)d_in[29];
  const float* hW1       = (const float*)d_in[30];
  const float* hb1       = (const float*)d_in[31];
  const float* hW2       = (const float*)d_in[32];
  const float* hb2       = (const float*)d_in[33];
  const float* hW3       = (const float*)d_in[34];
  const float* hb3       = (const float*)d_in[35];

  const int N = in_sizes[0];
  const int E = in_sizes[2];
  const int RB = 128;
  float* out = (float*)d_out;
  (void)n_in;

  char* ws = (char*)d_ws;
  size_t pos = 0;
  auto alloc = [&](size_t bytes) -> char* {
    char* p = ws + pos;
    pos = (pos + bytes + 255) & ~(size_t)255;
    return p;
  };
  int*    off   = (int*)   alloc((GNUM + 1) * sizeof(int));
  float*  hbuf0 = (float*) alloc((size_t)N * EMBD * 4);
  float*  hbuf1 = (float*) alloc((size_t)N * EMBD * 4);
  double* psum  = (double*)alloc((size_t)RB * 600 * 8);
  double* psq   = (double*)alloc((size_t)RB * 600 * 8);
  float*  vn    = (float*) alloc((size_t)GNUM * EMBD * 4);
  float*  vtmp  = (float*) alloc((size_t)GNUM * EMBD * 4);
  float*  vnraw = (float*) alloc((size_t)GNUM * EMBD * 4);
  double* cbuf  = (double*)alloc(EMBD * 8);
  int*    off2  = (int*)   alloc((size_t)(N + 1) * 4);
  int*    eix   = (int*)   alloc((size_t)E * 4);
  short*  wsplit1 = (short*)alloc((size_t)600 * 320 * 3 * 2);
  short*  wsplit2 = (short*)alloc((size_t)300 * 608 * 3 * 2);
  float*  s1    = (float*) alloc(600 * 4);
  float*  sh1   = (float*) alloc(600 * 4);
  float*  s2    = (float*) alloc(EMBD * 4);
  float*  sh2   = (float*) alloc(EMBD * 4);
  float*  vs1   = (float*) alloc(600 * 4);
  float*  vsh1  = (float*) alloc(600 * 4);
  float*  vs2   = (float*) alloc(EMBD * 4);
  float*  vsh2  = (float*) alloc(EMBD * 4);

  const size_t gpartBytes = (size_t)GRAM_KB * 15 * 4096 * 8;
  const size_t gBytes     = (size_t)EMBD * EMBD * 8;
  const size_t csrScratch = (size_t)N * 4 * 3 + 4096;
  const long long CH_MIN  = 2048;
  size_t slack = 1u << 20;
  size_t region_need = gpartBytes + gBytes;
  if (region_need < csrScratch) region_need = csrScratch;
  size_t t1_min = (size_t)CH_MIN * 600 * 4;
  if (region_need < t1_min) region_need = t1_min;

  if (ws_size < pos + region_need + slack) {
    float v = 1000.f + (float)(ws_size >> 20);
    k_diag<<<(out_size + 255) / 256, 256, 0, stream>>>(out, out_size, v);
    return;
  }

  size_t regionBytes = ws_size - pos - slack;
  char* region = ws + pos;
  int* deg  = (int*)region;
  int* incl = (int*)(region + (size_t)N * 4);
  int* cur  = (int*)(region + (size_t)N * 8);
  int* part = (int*)(region + (size_t)N * 12);
  double* gpart = (double*)region;
  double* G     = (double*)(region + gpartBytes);
  float*  t1buf = (float*)region;
  int CH;
  {
    long long ch = (long long)(regionBytes / (600ull * 4ull));
    if (ch > 32768) ch = 32768;
    ch &= ~63LL;
    if (ch < CH_MIN) ch = CH_MIN;
    long long npad = ((long long)N + 63) & ~63LL;
    if (ch > npad && npad >= CH_MIN) ch = npad;
    CH = (int)ch;
  }
  float* v1 = t1buf;
  float* hg     = vnraw;
  float* logits = t1buf;
  float* msgw   = t1buf + (size_t)GNUM * EMBD;
  float* dis    = vtmp;
  float* o1     = vn;
  float* o2     = vn + (size_t)GNUM * 128;

  k_zero<<<(GNUM * EMBD + 255) / 256, 256, 0, stream>>>(vn, GNUM * EMBD);
  k_offsets<<<(GNUM + 1 + 255) / 256, 256, 0, stream>>>(batch, N, off);

  const int* esrc = eidx;
  const int* edst = eidx + E;

  // CSR build (once)
  {
    int NB = (N + 255) / 256;
    k_seti<<<(N + 255) / 256, 256, 0, stream>>>(deg, N, 0);
    k_deg<<<(E + 255) / 256, 256, 0, stream>>>(edst, E, deg);
    k_scan1<<<NB, 256, 0, stream>>>(deg, N, incl, part);
    k_scan2<<<1, 512, 0, stream>>>(part, NB);
    k_scan3<<<(N + 255) / 256, 256, 0, stream>>>(deg, incl, part, N, E, off2);
    k_copyi<<<(N + 255) / 256, 256, 0, stream>>>(off2, cur, N);
    k_fill<<<(E + 255) / 256, 256, 0, stream>>>(edst, E, cur, eix);
  }

  float* hb[2] = {hbuf0, hbuf1};

  for (int l = 0; l < NLAY; l++) {
    float* tac = hb[l & 1];
    float* hlb = hb[(l + 1) & 1];

    if (l == 0)
      k_hl<true><<<N, 320, 0, stream>>>(atom_emb, x_idx, nullptr, nullptr, batch, vn, eps, l, tac, hlb, N);
    else
      k_hl<false><<<N, 320, 0, stream>>>(nullptr, nullptr, s2, sh2, batch, vn, eps, l, tac, hlb, N);

    k_gather<<<(N + 3) / 4, 256, 0, stream>>>(off2, eix, esrc, eattr, hlb,
                                              bond_emb + (size_t)l * 5 * EMBD, tac, N);

    if (l < NLAY - 1)
      k_vnseg<<<GNUM, 320, 0, stream>>>(hlb, off, vn, vtmp);

    // BN1 stats via Gram identity (MFMA gram)
    k_colstats<<<dim3(5, RB), 256, 0, stream>>>(tac, N, EMBD, psum, psq);
    k_redcol<<<2, 256, 0, stream>>>(psum, RB, EMBD, cbuf);
    k_mgram<<<dim3(15, GRAM_KB), 256, 0, stream>>>(tac, N, gpart);
    k_gramfin<<<240, 256, 0, stream>>>(gpart, G);
    k_bn1gram<<<600, 256, 0, stream>>>(G, cbuf, gin_W1 + (size_t)l * EMBD * 600,
                                       gin_b1 + (size_t)l * 600,
                                       gin_bn1_g + (size_t)l * 600, gin_bn1_b + (size_t)l * 600,
                                       N, s1, sh1);

    // pre-split weights into bf16 planes
    k_splitW<<<(600 * 320 + 255) / 256, 256, 0, stream>>>(gin_W1 + (size_t)l * EMBD * 600, 300, 320, 600, wsplit1);
    k_splitW<<<(300 * 608 + 255) / 256, 256, 0, stream>>>(gin_W2 + (size_t)l * 600 * EMBD, 600, 608, 300, wsplit2);

    // chunked split-MFMA GEMM1 (CT=2) -> t1buf -> GEMM2 (CT=1) -> h rows
    for (int r0 = 0; r0 < N; r0 += CH) {
      int nr = (N - r0 < CH) ? (N - r0) : CH;
      dim3 g1((nr + 63) / 64, 5);
      k_mgemm<2, false><<<g1, 256, 0, stream>>>(tac + (size_t)r0 * EMBD, wsplit1,
                                                gin_b1 + (size_t)l * 600, t1buf,
                                                nr, 300, 320, 600, nullptr, nullptr);
      dim3 g2((nr + 63) / 64, 5);
      k_mgemm<1, true><<<g2, 256, 0, stream>>>(t1buf, wsplit2,
                                               gin_b2 + (size_t)l * EMBD, hlb + (size_t)r0 * EMBD,
                                               nr, 600, 608, 300, s1, sh1);
    }
    k_colstats<<<dim3(5, RB), 256, 0, stream>>>(hlb, N, EMBD, psum, psq);
    k_finstats<<<EMBD, 256, 0, stream>>>(psum, psq, RB, EMBD, N,
                                         node_bn_g + (size_t)l * EMBD, node_bn_b + (size_t)l * EMBD, s2, sh2);

    if (l < NLAY - 1) {
      gemm<false, false>(vtmp, vn_W1 + (size_t)l * EMBD * 600, vn_b1 + (size_t)l * 600, v1,
                         GNUM, EMBD, 600, nullptr, nullptr, stream);
      k_colstats<<<dim3(10, RB), 256, 0, stream>>>(v1, GNUM, 600, psum, psq);
      k_finstats<<<600, 256, 0, stream>>>(psum, psq, RB, 600, GNUM,
                                          vn_bn1_g + (size_t)l * 600, vn_bn1_b + (size_t)l * 600, vs1, vsh1);
      gemm<true, false>(v1, vn_W2 + (size_t)l * 600 * EMBD, vn_b2 + (size_t)l * EMBD, vnraw,
                        GNUM, 600, EMBD, vs1, vsh1, stream);
      k_colstats<<<dim3(5, RB), 256, 0, stream>>>(vnraw, GNUM, EMBD, psum, psq);
      k_finstats<<<EMBD, 256, 0, stream>>>(psum, psq, RB, EMBD, GNUM,
                                           vn_bn2_g + (size_t)l * EMBD, vn_bn2_b + (size_t)l * EMBD, vs2, vsh2);
      k_vnfinal<<<(GNUM * EMBD + 255) / 256, 256, 0, stream>>>(vnraw, vs2, vsh2, vn, GNUM * EMBD);
    }
  }

  float* lastH = hb[NLAY & 1];
  k_pool<<<GNUM, 320, 0, stream>>>(lastH, off, s2, sh2, hg);

  gemm<false, false>(hg, pre_W, pre_b, logits, GNUM, EMBD, LSEM * VSEM, nullptr, nullptr, stream);
  k_sem<<<(GNUM * LSEM + 255) / 256, 256, 0, stream>>>(logits, gumbel, sel_W, sel_b, msgw);
  gemm<false, false>(msgw, aft_W, aft_b, dis, GNUM, 3 * LSEM, EMBD, nullptr, nullptr, stream);
  gemm<false, true>(dis, hW1, hb1, o1, GNUM, EMBD, 128, nullptr, nullptr, stream);
  gemm<false, true>(o1, hW2, hb2, o2, GNUM, 128, 128, nullptr, nullptr, stream);
  gemm<false, false>(o2, hW3, hb3, out, GNUM, 128, 128, nullptr, nullptr, stream);
}

// Round 20
// 9796.635 us; speedup vs baseline: 1.0680x; 1.0006x over previous
//
#include <hip/hip_runtime.h>
#include <cstdint>

#define EMBD 300
#define GNUM 2048
#define LSEM 10
#define VSEM 30
#define NLAY 5
#define GRAM_KB 24

typedef __attribute__((ext_vector_type(8))) short short8v;
typedef __attribute__((ext_vector_type(4))) float f32x4;

// exact fp32 -> 3x bf16 split (integer RNE; weight pre-split)
__device__ __forceinline__ void split3(float x, short& h1, short& h2, short& h3) {
  unsigned u = __float_as_uint(x);
  unsigned uh = (u + 0x7FFFu + ((u >> 16) & 1u)) & 0xFFFF0000u;
  h1 = (short)(uh >> 16);
  float r = x - __uint_as_float(uh);
  unsigned v = __float_as_uint(r);
  unsigned vh = (v + 0x7FFFu + ((v >> 16) & 1u)) & 0xFFFF0000u;
  h2 = (short)(vh >> 16);
  float r2 = r - __uint_as_float(vh);
  unsigned w = __float_as_uint(r2);
  unsigned wh = (w + 0x7FFFu + ((w >> 16) & 1u)) & 0xFFFF0000u;
  h3 = (short)(wh >> 16);
}

// packed fp32x2 -> bf16x2 (1 HW instr)
__device__ __forceinline__ unsigned cvt_pk_bf16(float lo, float hi) {
  unsigned r;
  asm("v_cvt_pk_bf16_f32 %0, %1, %2" : "=v"(r) : "v"(lo), "v"(hi));
  return r;
}

// split a PAIR of fp32 into 3 packed-bf16 limbs (residuals exact)
__device__ __forceinline__ void split3_pair(float x0, float x1,
                                            unsigned& u1, unsigned& u2, unsigned& u3) {
  u1 = cvt_pk_bf16(x0, x1);
  float r0 = x0 - __uint_as_float(u1 << 16);
  float r1 = x1 - __uint_as_float(u1 & 0xFFFF0000u);
  u2 = cvt_pk_bf16(r0, r1);
  float s0 = r0 - __uint_as_float(u2 << 16);
  float s1 = r1 - __uint_as_float(u2 & 0xFFFF0000u);
  u3 = cvt_pk_bf16(s0, s1);
}

// ---------------- diagnostics / utility ----------------
__global__ void k_diag(float* __restrict__ p, int n, float v) {
  int i = blockIdx.x * blockDim.x + threadIdx.x;
  if (i < n) p[i] = v;
}

__global__ void k_zero(float* __restrict__ p, int n) {
  int i = blockIdx.x * blockDim.x + threadIdx.x;
  if (i < n) p[i] = 0.f;
}

__global__ void k_seti(int* __restrict__ p, int n, int v) {
  int i = blockIdx.x * blockDim.x + threadIdx.x;
  if (i < n) p[i] = v;
}

// offsets via binary search (batch is sorted)
__global__ void k_offsets(const int* __restrict__ batch, int N, int* __restrict__ off) {
  int g = blockIdx.x * blockDim.x + threadIdx.x;
  if (g > GNUM) return;
  int lo = 0, hi = N;
  while (lo < hi) { int mid = (lo + hi) >> 1; if (batch[mid] < g) lo = mid + 1; else hi = mid; }
  off[g] = lo;
}

// ---------------- CSR build ----------------
__global__ void k_deg(const int* __restrict__ dst, int E, int* __restrict__ deg) {
  int e = blockIdx.x * blockDim.x + threadIdx.x;
  if (e < E) atomicAdd(&deg[dst[e]], 1);
}

__global__ void k_scan1(const int* __restrict__ deg, int N,
                        int* __restrict__ incl, int* __restrict__ part) {
  __shared__ int s[256];
  int tid = threadIdx.x;
  int i = blockIdx.x * 256 + tid;
  int v = (i < N) ? deg[i] : 0;
  s[tid] = v; __syncthreads();
  for (int o = 1; o < 256; o <<= 1) {
    int t = (tid >= o) ? s[tid - o] : 0;
    __syncthreads();
    s[tid] += t;
    __syncthreads();
  }
  if (i < N) incl[i] = s[tid];
  if (tid == 255) part[blockIdx.x] = s[255];
}

__global__ void k_scan2(int* __restrict__ part, int nb) {
  __shared__ int s[512];
  int t = threadIdx.x;
  if (nb <= 512) {
    int v = (t < nb) ? part[t] : 0;
    s[t] = v; __syncthreads();
    for (int o = 1; o < 512; o <<= 1) {
      int u = (t >= o) ? s[t - o] : 0;
      __syncthreads();
      s[t] += u;
      __syncthreads();
    }
    if (t < nb) part[t] = s[t] - v;
  } else if (t == 0) {
    int run = 0;
    for (int i = 0; i < nb; i++) { int x = part[i]; part[i] = run; run += x; }
  }
}

__global__ void k_scan3(const int* __restrict__ deg, const int* __restrict__ incl,
                        const int* __restrict__ part, int N, int E, int* __restrict__ off2) {
  int i = blockIdx.x * blockDim.x + threadIdx.x;
  if (i < N) off2[i] = part[i >> 8] + incl[i] - deg[i];
  if (i == 0) off2[N] = E;
}

__global__ void k_copyi(const int* __restrict__ a, int* __restrict__ b, int n) {
  int i = blockIdx.x * blockDim.x + threadIdx.x;
  if (i < n) b[i] = a[i];
}

__global__ void k_fill(const int* __restrict__ dst, int E,
                       int* __restrict__ cur, int* __restrict__ eix) {
  int e = blockIdx.x * blockDim.x + threadIdx.x;
  if (e >= E) return;
  int p = atomicAdd(&cur[dst[e]], 1);
  eix[p] = e;
}

// ---------------- hl / tacc ----------------
template<bool FIRST>
__global__ void k_hl(const float* __restrict__ aemb, const int* __restrict__ x_idx,
                     const float* __restrict__ scale, const float* __restrict__ shift,
                     const int* __restrict__ batch, const float* __restrict__ vn,
                     const float* __restrict__ epsArr, int l,
                     float* pt, float* __restrict__ hl, int N)
{
  int i = blockIdx.x;
  int c = threadIdx.x;
  if (c >= EMBD) return;
  float x;
  if (FIRST) {
    x = aemb[(size_t)x_idx[i] * EMBD + c];
  } else {
    x = pt[(size_t)i * EMBD + c];
    x = fmaxf(fmaf(x, scale[c], shift[c]), 0.f);
  }
  float h = x + vn[(size_t)batch[i] * EMBD + c];
  hl[(size_t)i * EMBD + c] = h;
  pt[(size_t)i * EMBD + c] = (1.f + epsArr[l]) * h;
}

// ---------------- CSR gather (2-edge ILP, XCD-aware bijective swizzle) ----------------
__global__ void k_gather(const int* __restrict__ off2, const int* __restrict__ eix,
                         const int* __restrict__ src, const int* __restrict__ eattr,
                         const float* __restrict__ hl, const float* __restrict__ bond,
                         float* __restrict__ tacc, int N)
{
  // bijective XCD swizzle (m204 form): consecutive-bid blocks land on the same XCD
  // with a CONTIGUOUS node range -> neighbor hl rows become L2-local.
  int bid = blockIdx.x;
  int nwg = gridDim.x;
  int q = nwg >> 3, r = nwg & 7;
  int xcd = bid & 7, idx = bid >> 3;
  int swz = (xcd < r ? xcd * (q + 1) : r * (q + 1) + (xcd - r) * q) + idx;
  int node = swz * 4 + (threadIdx.x >> 6);
  int lane = threadIdx.x & 63;
  if (node >= N) return;
  int p0 = off2[node], p1 = off2[node + 1];
  if (p0 == p1) return;
  float acc[5] = {0.f, 0.f, 0.f, 0.f, 0.f};
  int p = p0;
  for (; p + 1 < p1; p += 2) {
    int eA = eix[p], eB = eix[p + 1];
    int sA = src[eA], aA = eattr[eA];
    int sB = src[eB], aB = eattr[eB];
    const float* hA = hl + (size_t)sA * EMBD;
    const float* bA = bond + (size_t)aA * EMBD;
    const float* hB = hl + (size_t)sB * EMBD;
    const float* bB = bond + (size_t)aB * EMBD;
    #pragma unroll
    for (int qq = 0; qq < 5; qq++) {
      int c = lane + qq * 64;
      if (c < EMBD) {
        acc[qq] += fmaxf(hA[c] + bA[c], 0.f);
        acc[qq] += fmaxf(hB[c] + bB[c], 0.f);
      }
    }
  }
  if (p < p1) {
    int e = eix[p];
    int s = src[e], a = eattr[e];
    const float* hr = hl + (size_t)s * EMBD;
    const float* br = bond + (size_t)a * EMBD;
    #pragma unroll
    for (int qq = 0; qq < 5; qq++) {
      int c = lane + qq * 64;
      if (c < EMBD) acc[qq] += fmaxf(hr[c] + br[c], 0.f);
    }
  }
  float* tr = tacc + (size_t)node * EMBD;
  #pragma unroll
  for (int qq = 0; qq < 5; qq++) {
    int c = lane + qq * 64;
    if (c < EMBD) tr[c] += acc[qq];
  }
}

// ---------------- W split: [K][M] fp32 -> 3 bf16 planes [M][Kpad] ----------------
__global__ void k_splitW(const float* __restrict__ W, int K, int Kpad, int M,
                         short* __restrict__ planes)
{
  int idx = blockIdx.x * 256 + threadIdx.x;
  if (idx >= M * Kpad) return;
  int m = idx / Kpad, k = idx - m * Kpad;
  float x = (k < K) ? W[(size_t)k * M + m] : 0.f;
  short h1, h2, h3; split3(x, h1, h2, h3);
  size_t ps = (size_t)M * Kpad;
  planes[idx] = h1; planes[ps + idx] = h2; planes[2 * ps + idx] = h3;
}

// ---------------- split-bf16 MFMA GEMM, CT*64-col tiles (proven) ----------------
template<int CT, bool AFUSE>
__global__ __launch_bounds__(256) void k_mgemm(
    const float* __restrict__ A, const short* __restrict__ Wp,
    const float* __restrict__ bias, float* __restrict__ C,
    int n, int K, int Kpad, int M,
    const float* __restrict__ ascale, const float* __restrict__ ashift)
{
  __shared__ __align__(16) short lsA[3][64][40];
  __shared__ __align__(16) short lsB[3][CT * 64][40];
  int tid = threadIdx.x;
  int row0 = blockIdx.x * 64;
  int col0 = blockIdx.y * (CT * 64);
  int l = tid & 63, wid = tid >> 6;
  int wr = wid >> 1, wc = wid & 1;
  int lr = l & 15, kb = (l >> 4) * 8, rbase = (l >> 4) * 4;
  int sar = tid >> 2;
  int sak = (tid & 3) * 8;
  size_t planeSz = (size_t)M * Kpad;

  f32x4 acc[2][CT * 2];
  #pragma unroll
  for (int i = 0; i < 2; i++)
    #pragma unroll
    for (int j = 0; j < CT * 2; j++) acc[i][j] = (f32x4){0.f, 0.f, 0.f, 0.f};

  for (int k0 = 0; k0 < Kpad; k0 += 32) {
    {
      int gr = row0 + sar;
      int kbase = k0 + sak;
      float x[8];
      if (gr < n && kbase + 7 < K) {
        const float* ap = A + (size_t)gr * K + kbase;
        float4 u0 = *reinterpret_cast<const float4*>(ap);
        float4 u1 = *reinterpret_cast<const float4*>(ap + 4);
        x[0] = u0.x; x[1] = u0.y; x[2] = u0.z; x[3] = u0.w;
        x[4] = u1.x; x[5] = u1.y; x[6] = u1.z; x[7] = u1.w;
        if (AFUSE) {
          float4 sc0 = *reinterpret_cast<const float4*>(ascale + kbase);
          float4 sc1 = *reinterpret_cast<const float4*>(ascale + kbase + 4);
          float4 sf0 = *reinterpret_cast<const float4*>(ashift + kbase);
          float4 sf1 = *reinterpret_cast<const float4*>(ashift + kbase + 4);
          x[0] = fmaxf(fmaf(x[0], sc0.x, sf0.x), 0.f);
          x[1] = fmaxf(fmaf(x[1], sc0.y, sf0.y), 0.f);
          x[2] = fmaxf(fmaf(x[2], sc0.z, sf0.z), 0.f);
          x[3] = fmaxf(fmaf(x[3], sc0.w, sf0.w), 0.f);
          x[4] = fmaxf(fmaf(x[4], sc1.x, sf1.x), 0.f);
          x[5] = fmaxf(fmaf(x[5], sc1.y, sf1.y), 0.f);
          x[6] = fmaxf(fmaf(x[6], sc1.z, sf1.z), 0.f);
          x[7] = fmaxf(fmaf(x[7], sc1.w, sf1.w), 0.f);
        }
      } else {
        #pragma unroll
        for (int j = 0; j < 8; j++) {
          int k = kbase + j;
          float v = 0.f;
          if (gr < n && k < K) {
            v = A[(size_t)gr * K + k];
            if (AFUSE) v = fmaxf(fmaf(v, ascale[k], ashift[k]), 0.f);
          }
          x[j] = v;
        }
      }
      uint4 q1, q2, q3;
      unsigned* p1 = (unsigned*)&q1; unsigned* p2 = (unsigned*)&q2; unsigned* p3 = (unsigned*)&q3;
      #pragma unroll
      for (int j = 0; j < 4; j++) split3_pair(x[2 * j], x[2 * j + 1], p1[j], p2[j], p3[j]);
      *reinterpret_cast<uint4*>(&lsA[0][sar][sak]) = q1;
      *reinterpret_cast<uint4*>(&lsA[1][sar][sak]) = q2;
      *reinterpret_cast<uint4*>(&lsA[2][sar][sak]) = q3;
    }
    if constexpr (CT == 2) {
      int sbc = tid >> 1;
      int sbk = (tid & 1) * 16;
      int gc = col0 + sbc;
      #pragma unroll
      for (int p = 0; p < 3; p++) {
        short8v v0, v1;
        if (gc < M) {
          const short* bp = Wp + (size_t)p * planeSz + (size_t)gc * Kpad + k0 + sbk;
          v0 = *reinterpret_cast<const short8v*>(bp);
          v1 = *reinterpret_cast<const short8v*>(bp + 8);
        } else {
          #pragma unroll
          for (int j = 0; j < 8; j++) { v0[j] = 0; v1[j] = 0; }
        }
        *reinterpret_cast<short8v*>(&lsB[p][sbc][sbk]) = v0;
        *reinterpret_cast<short8v*>(&lsB[p][sbc][sbk + 8]) = v1;
      }
    } else {
      int sbc = tid >> 2;
      int sbk = (tid & 3) * 8;
      int gc = col0 + sbc;
      #pragma unroll
      for (int p = 0; p < 3; p++) {
        short8v v0;
        if (gc < M) {
          const short* bp = Wp + (size_t)p * planeSz + (size_t)gc * Kpad + k0 + sbk;
          v0 = *reinterpret_cast<const short8v*>(bp);
        } else {
          #pragma unroll
          for (int j = 0; j < 8; j++) v0[j] = 0;
        }
        *reinterpret_cast<short8v*>(&lsB[p][sbc][sbk]) = v0;
      }
    }
    __syncthreads();
    short8v fa[3][2];
    #pragma unroll
    for (int p = 0; p < 3; p++)
      #pragma unroll
      for (int rf = 0; rf < 2; rf++)
        fa[p][rf] = *reinterpret_cast<const short8v*>(&lsA[p][wr * 32 + rf * 16 + lr][kb]);
    #pragma unroll
    for (int cf = 0; cf < CT * 2; cf++) {
      int bcol = wc * (CT * 32) + cf * 16 + lr;
      short8v fb0 = *reinterpret_cast<const short8v*>(&lsB[0][bcol][kb]);
      short8v fb1 = *reinterpret_cast<const short8v*>(&lsB[1][bcol][kb]);
      short8v fb2 = *reinterpret_cast<const short8v*>(&lsB[2][bcol][kb]);
      #pragma unroll
      for (int rf = 0; rf < 2; rf++) {
        f32x4 a = acc[rf][cf];
        a = __builtin_amdgcn_mfma_f32_16x16x32_bf16(fa[0][rf], fb0, a, 0, 0, 0);
        a = __builtin_amdgcn_mfma_f32_16x16x32_bf16(fa[0][rf], fb1, a, 0, 0, 0);
        a = __builtin_amdgcn_mfma_f32_16x16x32_bf16(fa[1][rf], fb0, a, 0, 0, 0);
        a = __builtin_amdgcn_mfma_f32_16x16x32_bf16(fa[1][rf], fb1, a, 0, 0, 0);
        a = __builtin_amdgcn_mfma_f32_16x16x32_bf16(fa[0][rf], fb2, a, 0, 0, 0);
        a = __builtin_amdgcn_mfma_f32_16x16x32_bf16(fa[2][rf], fb0, a, 0, 0, 0);
        acc[rf][cf] = a;
      }
    }
    __syncthreads();
  }
  #pragma unroll
  for (int rf = 0; rf < 2; rf++) {
    #pragma unroll
    for (int cf = 0; cf < CT * 2; cf++) {
      int col = col0 + wc * (CT * 32) + cf * 16 + lr;
      if (col >= M) continue;
      float bv = bias[col];
      #pragma unroll
      for (int r = 0; r < 4; r++) {
        int row = row0 + wr * 32 + rf * 16 + rbase + r;
        if (row < n) C[(size_t)row * M + col] = acc[rf][cf][r] + bv;
      }
    }
  }
}

// ---------------- MFMA Gram ----------------
__global__ __launch_bounds__(256) void k_mgram(const float* __restrict__ A, int N,
                                               double* __restrict__ gpart)
{
  int bx = blockIdx.x;
  int ti = 0;
  {
    const int o1 = 5, o2 = 9, o3 = 12, o4 = 14;
    if (bx >= o1) ti = 1;
    if (bx >= o2) ti = 2;
    if (bx >= o3) ti = 3;
    if (bx >= o4) ti = 4;
  }
  const int offs[5] = {0, 5, 9, 12, 14};
  int tj = ti + (bx - offs[ti]);
  int I = ti * 64, J = tj * 64;
  __shared__ __align__(16) short lsI[3][64][40];
  __shared__ __align__(16) short lsJ[3][64][40];
  int tid = threadIdx.x;
  int l = tid & 63, wid = tid >> 6;
  int wr = wid >> 1, wc = wid & 1;
  int lr = l & 15, kb = (l >> 4) * 8, rbase = (l >> 4) * 4;
  int sr = tid & 31;
  int sc0 = (tid >> 5) * 8;

  f32x4 acc[2][2];
  #pragma unroll
  for (int i = 0; i < 2; i++)
    #pragma unroll
    for (int j = 0; j < 2; j++) acc[i][j] = (f32x4){0.f, 0.f, 0.f, 0.f};

  for (int r0 = blockIdx.y * 32; r0 < N; r0 += gridDim.y * 32) {
    int gr = r0 + sr;
    float xi[8], xj[8];
    {
      int ci = I + sc0;
      if (gr < N && ci + 7 < EMBD) {
        const float* ap = A + (size_t)gr * EMBD + ci;
        float4 u0 = *reinterpret_cast<const float4*>(ap);
        float4 u1 = *reinterpret_cast<const float4*>(ap + 4);
        xi[0] = u0.x; xi[1] = u0.y; xi[2] = u0.z; xi[3] = u0.w;
        xi[4] = u1.x; xi[5] = u1.y; xi[6] = u1.z; xi[7] = u1.w;
      } else {
        #pragma unroll
        for (int j = 0; j < 8; j++) {
          int c = ci + j;
          xi[j] = (gr < N && c < EMBD) ? A[(size_t)gr * EMBD + c] : 0.f;
        }
      }
      int cj = J + sc0;
      if (gr < N && cj + 7 < EMBD) {
        const float* ap = A + (size_t)gr * EMBD + cj;
        float4 u0 = *reinterpret_cast<const float4*>(ap);
        float4 u1 = *reinterpret_cast<const float4*>(ap + 4);
        xj[0] = u0.x; xj[1] = u0.y; xj[2] = u0.z; xj[3] = u0.w;
        xj[4] = u1.x; xj[5] = u1.y; xj[6] = u1.z; xj[7] = u1.w;
      } else {
        #pragma unroll
        for (int j = 0; j < 8; j++) {
          int c = cj + j;
          xj[j] = (gr < N && c < EMBD) ? A[(size_t)gr * EMBD + c] : 0.f;
        }
      }
    }
    #pragma unroll
    for (int j = 0; j < 8; j++) {
      short a1, a2, a3; split3(xi[j], a1, a2, a3);
      lsI[0][sc0 + j][sr] = a1; lsI[1][sc0 + j][sr] = a2; lsI[2][sc0 + j][sr] = a3;
      short b1, b2, b3; split3(xj[j], b1, b2, b3);
      lsJ[0][sc0 + j][sr] = b1; lsJ[1][sc0 + j][sr] = b2; lsJ[2][sc0 + j][sr] = b3;
    }
    __syncthreads();
    short8v fa[3][2];
    #pragma unroll
    for (int p = 0; p < 3; p++)
      #pragma unroll
      for (int rf = 0; rf < 2; rf++)
        fa[p][rf] = *reinterpret_cast<const short8v*>(&lsI[p][wr * 32 + rf * 16 + lr][kb]);
    #pragma unroll
    for (int cf = 0; cf < 2; cf++) {
      int bcol = wc * 32 + cf * 16 + lr;
      short8v fb0 = *reinterpret_cast<const short8v*>(&lsJ[0][bcol][kb]);
      short8v fb1 = *reinterpret_cast<const short8v*>(&lsJ[1][bcol][kb]);
      short8v fb2 = *reinterpret_cast<const short8v*>(&lsJ[2][bcol][kb]);
      #pragma unroll
      for (int rf = 0; rf < 2; rf++) {
        f32x4 a = acc[rf][cf];
        a = __builtin_amdgcn_mfma_f32_16x16x32_bf16(fa[0][rf], fb0, a, 0, 0, 0);
        a = __builtin_amdgcn_mfma_f32_16x16x32_bf16(fa[0][rf], fb1, a, 0, 0, 0);
        a = __builtin_amdgcn_mfma_f32_16x16x32_bf16(fa[1][rf], fb0, a, 0, 0, 0);
        a = __builtin_amdgcn_mfma_f32_16x16x32_bf16(fa[1][rf], fb1, a, 0, 0, 0);
        a = __builtin_amdgcn_mfma_f32_16x16x32_bf16(fa[0][rf], fb2, a, 0, 0, 0);
        a = __builtin_amdgcn_mfma_f32_16x16x32_bf16(fa[2][rf], fb0, a, 0, 0, 0);
        acc[rf][cf] = a;
      }
    }
    __syncthreads();
  }
  size_t base = ((size_t)blockIdx.y * 15 + bx) * 4096;
  #pragma unroll
  for (int rf = 0; rf < 2; rf++)
    #pragma unroll
    for (int cf = 0; cf < 2; cf++) {
      int col = wc * 32 + cf * 16 + lr;
      #pragma unroll
      for (int r = 0; r < 4; r++) {
        int row = wr * 32 + rf * 16 + rbase + r;
        gpart[base + (size_t)row * 64 + col] = (double)acc[rf][cf][r];
      }
    }
}

// ---------------- 64x64 fp32 GEMM (vn path / head) ----------------
template<bool AFUSE, bool ORELU>
__global__ __launch_bounds__(256) void k_gemm(
    const float* __restrict__ A, const float* __restrict__ W,
    const float* __restrict__ bias, float* __restrict__ C,
    int N, int K, int M,
    const float* __restrict__ ascale, const float* __restrict__ ashift)
{
  __shared__ __align__(16) float As[16][72];
  __shared__ __align__(16) float Bs[16][72];
  int tid = threadIdx.x;
  int row0 = blockIdx.x * 64;
  int col0 = blockIdx.y * 64;
  int tx = tid & 15, ty = tid >> 4;
  bool kvec = ((K & 3) == 0);
  bool mvec = ((M & 3) == 0);
  float acc[4][4] = {};
  for (int k0 = 0; k0 < K; k0 += 16) {
    {
      int r = tid >> 2;
      int kq = (tid & 3) * 4;
      int gr = row0 + r;
      float a0 = 0.f, a1 = 0.f, a2 = 0.f, a3 = 0.f;
      if (gr < N) {
        const float* ap = A + (size_t)gr * K + k0 + kq;
        int k = k0 + kq;
        if (kvec && k + 3 < K) {
          float4 t = *reinterpret_cast<const float4*>(ap);
          a0 = t.x; a1 = t.y; a2 = t.z; a3 = t.w;
        } else {
          if (k + 0 < K) a0 = ap[0];
          if (k + 1 < K) a1 = ap[1];
          if (k + 2 < K) a2 = ap[2];
          if (k + 3 < K) a3 = ap[3];
        }
        if (AFUSE) {
          if (k + 0 < K) a0 = fmaxf(fmaf(a0, ascale[k + 0], ashift[k + 0]), 0.f);
          if (k + 1 < K) a1 = fmaxf(fmaf(a1, ascale[k + 1], ashift[k + 1]), 0.f);
          if (k + 2 < K) a2 = fmaxf(fmaf(a2, ascale[k + 2], ashift[k + 2]), 0.f);
          if (k + 3 < K) a3 = fmaxf(fmaf(a3, ascale[k + 3], ashift[k + 3]), 0.f);
        }
      }
      As[kq + 0][r] = a0; As[kq + 1][r] = a1; As[kq + 2][r] = a2; As[kq + 3][r] = a3;
    }
    {
      int kk = tid >> 4;
      int j = (tid & 15) * 4;
      int gk = k0 + kk;
      float4 bv = {0.f, 0.f, 0.f, 0.f};
      if (gk < K) {
        const float* wp = W + (size_t)gk * M + col0 + j;
        if (mvec && col0 + j + 3 < M) {
          bv = *reinterpret_cast<const float4*>(wp);
        } else {
          if (col0 + j + 0 < M) bv.x = wp[0];
          if (col0 + j + 1 < M) bv.y = wp[1];
          if (col0 + j + 2 < M) bv.z = wp[2];
          if (col0 + j + 3 < M) bv.w = wp[3];
        }
      }
      *reinterpret_cast<float4*>(&Bs[kk][j]) = bv;
    }
    __syncthreads();
    #pragma unroll
    for (int kk = 0; kk < 16; kk++) {
      float4 a4 = *reinterpret_cast<const float4*>(&As[kk][ty * 4]);
      float4 b4 = *reinterpret_cast<const float4*>(&Bs[kk][tx * 4]);
      float a[4] = {a4.x, a4.y, a4.z, a4.w};
      float b[4] = {b4.x, b4.y, b4.z, b4.w};
      #pragma unroll
      for (int u = 0; u < 4; u++)
        #pragma unroll
        for (int v = 0; v < 4; v++)
          acc[u][v] = fmaf(a[u], b[v], acc[u][v]);
    }
    __syncthreads();
  }
  float bv[4];
  #pragma unroll
  for (int v = 0; v < 4; v++) { int gc = col0 + tx * 4 + v; bv[v] = (gc < M) ? bias[gc] : 0.f; }
  #pragma unroll
  for (int u = 0; u < 4; u++) {
    int gr = row0 + ty * 4 + u;
    if (gr >= N) continue;
    int gc0 = col0 + tx * 4;
    float val[4];
    #pragma unroll
    for (int v = 0; v < 4; v++) {
      float x = acc[u][v] + bv[v];
      if (ORELU) x = fmaxf(x, 0.f);
      val[v] = x;
    }
    if (mvec && gc0 + 3 < M) {
      float4 o = {val[0], val[1], val[2], val[3]};
      *reinterpret_cast<float4*>(C + (size_t)gr * M + gc0) = o;
    } else {
      #pragma unroll
      for (int v = 0; v < 4; v++) {
        int gc = gc0 + v;
        if (gc < M) C[(size_t)gr * M + gc] = val[v];
      }
    }
  }
}

__global__ void k_gramfin(const double* __restrict__ gpart, double* __restrict__ G)
{
  int e = blockIdx.x * 256 + threadIdx.x;
  if (e >= 15 * 4096) return;
  int tile = e >> 12;
  int ii = (e >> 6) & 63, jj = e & 63;
  const int tit[15] = {0,0,0,0,0,1,1,1,1,2,2,2,3,3,4};
  const int tjt[15] = {0,1,2,3,4,1,2,3,4,2,3,4,3,4,4};
  int gi = tit[tile] * 64 + ii, gj = tjt[tile] * 64 + jj;
  if (gi >= EMBD || gj >= EMBD) return;
  double s = 0.0;
  for (int kb = 0; kb < GRAM_KB; kb++)
    s += gpart[((size_t)kb * 15 + tile) * 4096 + ii * 64 + jj];
  G[(size_t)gi * EMBD + gj] = s;
  G[(size_t)gj * EMBD + gi] = s;
}

__global__ void k_bn1gram(const double* __restrict__ G, const double* __restrict__ cbuf,
                          const float* __restrict__ W1, const float* __restrict__ b1,
                          const float* __restrict__ g, const float* __restrict__ b,
                          int n, float* __restrict__ sc, float* __restrict__ sh)
{
  int j = blockIdx.x;
  int t = threadIdx.x;
  __shared__ double ws[EMBD];
  __shared__ double red[256];
  for (int k = t; k < EMBD; k += 256) ws[k] = (double)W1[(size_t)k * 600 + j];
  __syncthreads();
  int i1 = 256 + t;
  double y0 = 0.0, y1 = 0.0;
  for (int k = 0; k < EMBD; k++) {
    double wk = ws[k];
    y0 += G[(size_t)k * EMBD + t] * wk;
    if (i1 < EMBD) y1 += G[(size_t)k * EMBD + i1] * wk;
  }
  double part = ws[t] * y0 + ((i1 < EMBD) ? ws[i1] * y1 : 0.0);
  double dpart = cbuf[t] * ws[t] + ((i1 < EMBD) ? cbuf[i1] * ws[i1] : 0.0);
  red[t] = part; __syncthreads();
  for (int w = 128; w > 0; w >>= 1) { if (t < w) red[t] += red[t + w]; __syncthreads(); }
  double Q = red[0]; __syncthreads();
  red[t] = dpart; __syncthreads();
  for (int w = 128; w > 0; w >>= 1) { if (t < w) red[t] += red[t + w]; __syncthreads(); }
  if (t == 0) {
    double d = red[0];
    double bj = (double)b1[j];
    double S = d + (double)n * bj;
    double Qf = Q + 2.0 * bj * d + (double)n * bj * bj;
    double m = S / n;
    double var = Qf / n - m * m;
    double inv = 1.0 / sqrt(var + 1e-5);
    double scv = (double)g[j] * inv;
    sc[j] = (float)scv;
    sh[j] = (float)((double)b[j] - m * scv);
  }
}

// ---------------- column stats ----------------
__global__ void k_colstats(const float* __restrict__ X, int n, int C,
                           double* __restrict__ psum, double* __restrict__ psq)
{
  int tid = threadIdx.x;
  int col = blockIdx.x * 64 + (tid & 63);
  int rl = tid >> 6;
  double s = 0.0, q = 0.0;
  if (col < C) {
    int stride = gridDim.y * 4;
    for (int r = blockIdx.y * 4 + rl; r < n; r += stride) {
      double x = (double)X[(size_t)r * C + col];
      s += x; q += x * x;
    }
  }
  __shared__ double ls[2][4][64];
  ls[0][rl][tid & 63] = s;
  ls[1][rl][tid & 63] = q;
  __syncthreads();
  if (rl == 0 && col < C) {
    int c = tid & 63;
    double S = ls[0][0][c] + ls[0][1][c] + ls[0][2][c] + ls[0][3][c];
    double Q = ls[1][0][c] + ls[1][1][c] + ls[1][2][c] + ls[1][3][c];
    psum[(size_t)blockIdx.y * C + col] = S;
    psq [(size_t)blockIdx.y * C + col] = Q;
  }
}

__global__ void k_redcol(const double* __restrict__ psum, int R, int C, double* __restrict__ cbuf)
{
  int c = blockIdx.x * blockDim.x + threadIdx.x;
  if (c >= C) return;
  double s = 0.0;
  for (int r = 0; r < R; r++) s += psum[(size_t)r * C + c];
  cbuf[c] = s;
}

__global__ void k_finstats(const double* __restrict__ psum, const double* __restrict__ psq,
                           int R, int M, int n,
                           const float* __restrict__ g, const float* __restrict__ b,
                           float* __restrict__ sc, float* __restrict__ sh)
{
  int j = blockIdx.x;
  int t = threadIdx.x;
  double s = 0.0, q = 0.0;
  for (int r = t; r < R; r += 256) { s += psum[(size_t)r * M + j]; q += psq[(size_t)r * M + j]; }
  __shared__ double ls[256], lq[256];
  ls[t] = s; lq[t] = q; __syncthreads();
  for (int w = 128; w > 0; w >>= 1) {
    if (t < w) { ls[t] += ls[t + w]; lq[t] += lq[t + w]; }
    __syncthreads();
  }
  if (t == 0) {
    double m = ls[0] / n;
    double v = lq[0] / n - m * m;
    double inv = 1.0 / sqrt(v + 1e-5);
    double scv = (double)g[j] * inv;
    sc[j] = (float)scv;
    sh[j] = (float)((double)b[j] - m * scv);
  }
}

// ---------------- vn / pool / sem ----------------
__global__ void k_vnseg(const float* __restrict__ hl, const int* __restrict__ off,
                        const float* __restrict__ vn, float* __restrict__ vtmp)
{
  int g = blockIdx.x;
  int c = threadIdx.x;
  if (c >= EMBD) return;
  int r0 = off[g], r1 = off[g + 1];
  float s = 0.f;
  for (int r = r0; r < r1; r++) s += hl[(size_t)r * EMBD + c];
  vtmp[(size_t)g * EMBD + c] = s + vn[(size_t)g * EMBD + c];
}

__global__ void k_vnfinal(const float* __restrict__ vnraw, const float* __restrict__ scale,
                          const float* __restrict__ shift, float* __restrict__ vn, int total)
{
  int i = blockIdx.x * blockDim.x + threadIdx.x;
  if (i >= total) return;
  int c = i % EMBD;
  vn[i] = fmaxf(fmaf(vnraw[i], scale[c], shift[c]), 0.f);
}

__global__ void k_pool(const float* __restrict__ t2, const int* __restrict__ off,
                       const float* __restrict__ scale, const float* __restrict__ shift,
                       float* __restrict__ hg)
{
  int g = blockIdx.x;
  int c = threadIdx.x;
  if (c >= EMBD) return;
  int r0 = off[g], r1 = off[g + 1];
  float s = 0.f;
  for (int r = r0; r < r1; r++) s += t2[(size_t)r * EMBD + c];
  int cnt = r1 - r0;
  float denom = (cnt > 0) ? (float)cnt : 1.f;
  hg[(size_t)g * EMBD + c] = (scale[c] * s + shift[c] * (float)cnt) / denom;
}

__global__ void k_sem(const float* __restrict__ logits, const float* __restrict__ gum,
                      const float* __restrict__ selW, const float* __restrict__ selb,
                      float* __restrict__ msgw)
{
  int idx = blockIdx.x * blockDim.x + threadIdx.x;
  if (idx >= GNUM * LSEM) return;
  int g = idx / LSEM, l = idx % LSEM;
  const float* lp = logits + (size_t)g * (LSEM * VSEM) + l * VSEM;
  const float* gp = gum + (size_t)g * (LSEM * VSEM) + l * VSEM;
  float best = -1e30f; int bi = 0;
  for (int v = 0; v < VSEM; v++) {
    float y = lp[v] + gp[v];
    if (y > best) { best = y; bi = v; }
  }
  float* o = msgw + (size_t)g * (3 * LSEM) + l * 3;
  o[0] = selW[bi * 3 + 0] + selb[0];
  o[1] = selW[bi * 3 + 1] + selb[1];
  o[2] = selW[bi * 3 + 2] + selb[2];
}

// ---------------- host ----------------
template<bool AFUSE, bool ORELU>
static void gemm(const float* A, const float* W, const float* b, float* C,
                 int n, int k, int m, const float* sc, const float* sh, hipStream_t st)
{
  dim3 grid((n + 63) / 64, (m + 63) / 64);
  k_gemm<AFUSE, ORELU><<<grid, 256, 0, st>>>(A, W, b, C, n, k, m, sc, sh);
}

extern "C" void kernel_launch(void* const* d_in, const int* in_sizes, int n_in,
                              void* d_out, int out_size, void* d_ws, size_t ws_size,
                              hipStream_t stream)
{
  const int*   x_idx     = (const int*)d_in[0];
  const int*   eidx      = (const int*)d_in[1];
  const int*   eattr     = (const int*)d_in[2];
  const int*   batch     = (const int*)d_in[3];
  const float* gumbel    = (const float*)d_in[4];
  const float* atom_emb  = (const float*)d_in[5];
  const float* bond_emb  = (const float*)d_in[6];
  const float* eps       = (const float*)d_in[7];
  const float* gin_W1    = (const float*)d_in[8];
  const float* gin_b1    = (const float*)d_in[9];
  const float* gin_bn1_g = (const float*)d_in[10];
  const float* gin_bn1_b = (const float*)d_in[11];
  const float* gin_W2    = (const float*)d_in[12];
  const float* gin_b2    = (const float*)d_in[13];
  const float* node_bn_g = (const float*)d_in[14];
  const float* node_bn_b = (const float*)d_in[15];
  const float* vn_W1     = (const float*)d_in[16];
  const float* vn_b1     = (const float*)d_in[17];
  const float* vn_bn1_g  = (const float*)d_in[18];
  const float* vn_bn1_b  = (const float*)d_in[19];
  const float* vn_W2     = (const float*)d_in[20];
  const float* vn_b2     = (const float*)d_in[21];
  const float* vn_bn2_g  = (const float*)d_in[22];
  const float* vn_bn2_b  = (const float*)d_in[23];
  const float* pre_W     = (const float*)d_in[24];
  const float* pre_b     = (const float*)d_in[25];
  const float* sel_W     = (const float*)d_in[26];
  const float* sel_b     = (const float*)d_in[27];
  const float* aft_W     = (const float*)d_in[28];
  const float* aft_b     = (const float*)d_in[29];
  const float* hW1       = (const float*)d_in[30];
  const float* hb1       = (const float*)d_in[31];
  const float* hW2       = (const float*)d_in[32];
  const float* hb2       = (const float*)d_in[33];
  const float* hW3       = (const float*)d_in[34];
  const float* hb3       = (const float*)d_in[35];

  const int N = in_sizes[0];
  const int E = in_sizes[2];
  const int RB = 128;
  float* out = (float*)d_out;
  (void)n_in;

  char* ws = (char*)d_ws;
  size_t pos = 0;
  auto alloc = [&](size_t bytes) -> char* {
    char* p = ws + pos;
    pos = (pos + bytes + 255) & ~(size_t)255;
    return p;
  };
  int*    off   = (int*)   alloc((GNUM + 1) * sizeof(int));
  float*  hbuf0 = (float*) alloc((size_t)N * EMBD * 4);
  float*  hbuf1 = (float*) alloc((size_t)N * EMBD * 4);
  double* psum  = (double*)alloc((size_t)RB * 600 * 8);
  double* psq   = (double*)alloc((size_t)RB * 600 * 8);
  float*  vn    = (float*) alloc((size_t)GNUM * EMBD * 4);
  float*  vtmp  = (float*) alloc((size_t)GNUM * EMBD * 4);
  float*  vnraw = (float*) alloc((size_t)GNUM * EMBD * 4);
  double* cbuf  = (double*)alloc(EMBD * 8);
  int*    off2  = (int*)   alloc((size_t)(N + 1) * 4);
  int*    eix   = (int*)   alloc((size_t)E * 4);
  short*  wsplit1 = (short*)alloc((size_t)600 * 320 * 3 * 2);
  short*  wsplit2 = (short*)alloc((size_t)300 * 608 * 3 * 2);
  float*  s1    = (float*) alloc(600 * 4);
  float*  sh1   = (float*) alloc(600 * 4);
  float*  s2    = (float*) alloc(EMBD * 4);
  float*  sh2   = (float*) alloc(EMBD * 4);
  float*  vs1   = (float*) alloc(600 * 4);
  float*  vsh1  = (float*) alloc(600 * 4);
  float*  vs2   = (float*) alloc(EMBD * 4);
  float*  vsh2  = (float*) alloc(EMBD * 4);

  const size_t gpartBytes = (size_t)GRAM_KB * 15 * 4096 * 8;
  const size_t gBytes     = (size_t)EMBD * EMBD * 8;
  const size_t csrScratch = (size_t)N * 4 * 3 + 4096;
  const long long CH_MIN  = 2048;
  size_t slack = 1u << 20;
  size_t region_need = gpartBytes + gBytes;
  if (region_need < csrScratch) region_need = csrScratch;
  size_t t1_min = (size_t)CH_MIN * 600 * 4;
  if (region_need < t1_min) region_need = t1_min;

  if (ws_size < pos + region_need + slack) {
    float v = 1000.f + (float)(ws_size >> 20);
    k_diag<<<(out_size + 255) / 256, 256, 0, stream>>>(out, out_size, v);
    return;
  }

  size_t regionBytes = ws_size - pos - slack;
  char* region = ws + pos;
  int* deg  = (int*)region;
  int* incl = (int*)(region + (size_t)N * 4);
  int* cur  = (int*)(region + (size_t)N * 8);
  int* part = (int*)(region + (size_t)N * 12);
  double* gpart = (double*)region;
  double* G     = (double*)(region + gpartBytes);
  float*  t1buf = (float*)region;
  int CH;
  {
    long long ch = (long long)(regionBytes / (600ull * 4ull));
    if (ch > 32768) ch = 32768;
    ch &= ~63LL;
    if (ch < CH_MIN) ch = CH_MIN;
    long long npad = ((long long)N + 63) & ~63LL;
    if (ch > npad && npad >= CH_MIN) ch = npad;
    CH = (int)ch;
  }
  float* v1 = t1buf;
  float* hg     = vnraw;
  float* logits = t1buf;
  float* msgw   = t1buf + (size_t)GNUM * EMBD;
  float* dis    = vtmp;
  float* o1     = vn;
  float* o2     = vn + (size_t)GNUM * 128;

  k_zero<<<(GNUM * EMBD + 255) / 256, 256, 0, stream>>>(vn, GNUM * EMBD);
  k_offsets<<<(GNUM + 1 + 255) / 256, 256, 0, stream>>>(batch, N, off);

  const int* esrc = eidx;
  const int* edst = eidx + E;

  // CSR build (once)
  {
    int NB = (N + 255) / 256;
    k_seti<<<(N + 255) / 256, 256, 0, stream>>>(deg, N, 0);
    k_deg<<<(E + 255) / 256, 256, 0, stream>>>(edst, E, deg);
    k_scan1<<<NB, 256, 0, stream>>>(deg, N, incl, part);
    k_scan2<<<1, 512, 0, stream>>>(part, NB);
    k_scan3<<<(N + 255) / 256, 256, 0, stream>>>(deg, incl, part, N, E, off2);
    k_copyi<<<(N + 255) / 256, 256, 0, stream>>>(off2, cur, N);
    k_fill<<<(E + 255) / 256, 256, 0, stream>>>(edst, E, cur, eix);
  }

  float* hb[2] = {hbuf0, hbuf1};

  for (int l = 0; l < NLAY; l++) {
    float* tac = hb[l & 1];
    float* hlb = hb[(l + 1) & 1];

    if (l == 0)
      k_hl<true><<<N, 320, 0, stream>>>(atom_emb, x_idx, nullptr, nullptr, batch, vn, eps, l, tac, hlb, N);
    else
      k_hl<false><<<N, 320, 0, stream>>>(nullptr, nullptr, s2, sh2, batch, vn, eps, l, tac, hlb, N);

    k_gather<<<(N + 3) / 4, 256, 0, stream>>>(off2, eix, esrc, eattr, hlb,
                                              bond_emb + (size_t)l * 5 * EMBD, tac, N);

    if (l < NLAY - 1)
      k_vnseg<<<GNUM, 320, 0, stream>>>(hlb, off, vn, vtmp);

    // BN1 stats via Gram identity (MFMA gram)
    k_colstats<<<dim3(5, RB), 256, 0, stream>>>(tac, N, EMBD, psum, psq);
    k_redcol<<<2, 256, 0, stream>>>(psum, RB, EMBD, cbuf);
    k_mgram<<<dim3(15, GRAM_KB), 256, 0, stream>>>(tac, N, gpart);
    k_gramfin<<<240, 256, 0, stream>>>(gpart, G);
    k_bn1gram<<<600, 256, 0, stream>>>(G, cbuf, gin_W1 + (size_t)l * EMBD * 600,
                                       gin_b1 + (size_t)l * 600,
                                       gin_bn1_g + (size_t)l * 600, gin_bn1_b + (size_t)l * 600,
                                       N, s1, sh1);

    // pre-split weights into bf16 planes
    k_splitW<<<(600 * 320 + 255) / 256, 256, 0, stream>>>(gin_W1 + (size_t)l * EMBD * 600, 300, 320, 600, wsplit1);
    k_splitW<<<(300 * 608 + 255) / 256, 256, 0, stream>>>(gin_W2 + (size_t)l * 600 * EMBD, 600, 608, 300, wsplit2);

    // chunked split-MFMA GEMM1 (CT=2) -> t1buf -> GEMM2 (CT=1) -> h rows
    for (int r0 = 0; r0 < N; r0 += CH) {
      int nr = (N - r0 < CH) ? (N - r0) : CH;
      dim3 g1((nr + 63) / 64, 5);
      k_mgemm<2, false><<<g1, 256, 0, stream>>>(tac + (size_t)r0 * EMBD, wsplit1,
                                                gin_b1 + (size_t)l * 600, t1buf,
                                                nr, 300, 320, 600, nullptr, nullptr);
      dim3 g2((nr + 63) / 64, 5);
      k_mgemm<1, true><<<g2, 256, 0, stream>>>(t1buf, wsplit2,
                                               gin_b2 + (size_t)l * EMBD, hlb + (size_t)r0 * EMBD,
                                               nr, 600, 608, 300, s1, sh1);
    }
    k_colstats<<<dim3(5, RB), 256, 0, stream>>>(hlb, N, EMBD, psum, psq);
    k_finstats<<<EMBD, 256, 0, stream>>>(psum, psq, RB, EMBD, N,
                                         node_bn_g + (size_t)l * EMBD, node_bn_b + (size_t)l * EMBD, s2, sh2);

    if (l < NLAY - 1) {
      gemm<false, false>(vtmp, vn_W1 + (size_t)l * EMBD * 600, vn_b1 + (size_t)l * 600, v1,
                         GNUM, EMBD, 600, nullptr, nullptr, stream);
      k_colstats<<<dim3(10, RB), 256, 0, stream>>>(v1, GNUM, 600, psum, psq);
      k_finstats<<<600, 256, 0, stream>>>(psum, psq, RB, 600, GNUM,
                                          vn_bn1_g + (size_t)l * 600, vn_bn1_b + (size_t)l * 600, vs1, vsh1);
      gemm<true, false>(v1, vn_W2 + (size_t)l * 600 * EMBD, vn_b2 + (size_t)l * EMBD, vnraw,
                        GNUM, 600, EMBD, vs1, vsh1, stream);
      k_colstats<<<dim3(5, RB), 256, 0, stream>>>(vnraw, GNUM, EMBD, psum, psq);
      k_finstats<<<EMBD, 256, 0, stream>>>(psum, psq, RB, EMBD, GNUM,
                                           vn_bn2_g + (size_t)l * EMBD, vn_bn2_b + (size_t)l * EMBD, vs2, vsh2);
      k_vnfinal<<<(GNUM * EMBD + 255) / 256, 256, 0, stream>>>(vnraw, vs2, vsh2, vn, GNUM * EMBD);
    }
  }

  float* lastH = hb[NLAY & 1];
  k_pool<<<GNUM, 320, 0, stream>>>(lastH, off, s2, sh2, hg);

  gemm<false, false>(hg, pre_W, pre_b, logits, GNUM, EMBD, LSEM * VSEM, nullptr, nullptr, stream);
  k_sem<<<(GNUM * LSEM + 255) / 256, 256, 0, stream>>>(logits, gumbel, sel_W, sel_b, msgw);
  gemm<false, false>(msgw, aft_W, aft_b, dis, GNUM, 3 * LSEM, EMBD, nullptr, nullptr, stream);
  gemm<false, true>(dis, hW1, hb1, o1, GNUM, EMBD, 128, nullptr, nullptr, stream);
  gemm<false, true>(o1, hW2, hb2, o2, GNUM, 128, 128, nullptr, nullptr, stream);
  gemm<false, false>(o2, hW3, hb3, out, GNUM, 128, 128, nullptr, nullptr, stream);
}

// Round 21
// 9033.222 us; speedup vs baseline: 1.1583x; 1.0845x over previous
//
#include <hip/hip_runtime.h>
#include <cstdint>

#define EMBD 300
#define GNUM 2048
#define LSEM 10
#define VSEM 30
#define NLAY 5
#define GRAM_KB 24

typedef __attribute__((ext_vector_type(8))) short short8v;
typedef __attribute__((ext_vector_type(4))) float f32x4;

// exact fp32 -> 3x bf16 split (integer RNE; weight pre-split)
__device__ __forceinline__ void split3(float x, short& h1, short& h2, short& h3) {
  unsigned u = __float_as_uint(x);
  unsigned uh = (u + 0x7FFFu + ((u >> 16) & 1u)) & 0xFFFF0000u;
  h1 = (short)(uh >> 16);
  float r = x - __uint_as_float(uh);
  unsigned v = __float_as_uint(r);
  unsigned vh = (v + 0x7FFFu + ((v >> 16) & 1u)) & 0xFFFF0000u;
  h2 = (short)(vh >> 16);
  float r2 = r - __uint_as_float(vh);
  unsigned w = __float_as_uint(r2);
  unsigned wh = (w + 0x7FFFu + ((w >> 16) & 1u)) & 0xFFFF0000u;
  h3 = (short)(wh >> 16);
}

// packed fp32x2 -> bf16x2 (1 HW instr)
__device__ __forceinline__ unsigned cvt_pk_bf16(float lo, float hi) {
  unsigned r;
  asm("v_cvt_pk_bf16_f32 %0, %1, %2" : "=v"(r) : "v"(lo), "v"(hi));
  return r;
}

// split a PAIR of fp32 into 3 packed-bf16 limbs (residuals exact)
__device__ __forceinline__ void split3_pair(float x0, float x1,
                                            unsigned& u1, unsigned& u2, unsigned& u3) {
  u1 = cvt_pk_bf16(x0, x1);
  float r0 = x0 - __uint_as_float(u1 << 16);
  float r1 = x1 - __uint_as_float(u1 & 0xFFFF0000u);
  u2 = cvt_pk_bf16(r0, r1);
  float s0 = r0 - __uint_as_float(u2 << 16);
  float s1 = r1 - __uint_as_float(u2 & 0xFFFF0000u);
  u3 = cvt_pk_bf16(s0, s1);
}

// ---------------- diagnostics / utility ----------------
__global__ void k_diag(float* __restrict__ p, int n, float v) {
  int i = blockIdx.x * blockDim.x + threadIdx.x;
  if (i < n) p[i] = v;
}

__global__ void k_zero(float* __restrict__ p, int n) {
  int i = blockIdx.x * blockDim.x + threadIdx.x;
  if (i < n) p[i] = 0.f;
}

__global__ void k_seti(int* __restrict__ p, int n, int v) {
  int i = blockIdx.x * blockDim.x + threadIdx.x;
  if (i < n) p[i] = v;
}

// offsets via binary search (batch is sorted)
__global__ void k_offsets(const int* __restrict__ batch, int N, int* __restrict__ off) {
  int g = blockIdx.x * blockDim.x + threadIdx.x;
  if (g > GNUM) return;
  int lo = 0, hi = N;
  while (lo < hi) { int mid = (lo + hi) >> 1; if (batch[mid] < g) lo = mid + 1; else hi = mid; }
  off[g] = lo;
}

// ---------------- CSR build ----------------
__global__ void k_deg(const int* __restrict__ dst, int E, int* __restrict__ deg) {
  int e = blockIdx.x * blockDim.x + threadIdx.x;
  if (e < E) atomicAdd(&deg[dst[e]], 1);
}

__global__ void k_scan1(const int* __restrict__ deg, int N,
                        int* __restrict__ incl, int* __restrict__ part) {
  __shared__ int s[256];
  int tid = threadIdx.x;
  int i = blockIdx.x * 256 + tid;
  int v = (i < N) ? deg[i] : 0;
  s[tid] = v; __syncthreads();
  for (int o = 1; o < 256; o <<= 1) {
    int t = (tid >= o) ? s[tid - o] : 0;
    __syncthreads();
    s[tid] += t;
    __syncthreads();
  }
  if (i < N) incl[i] = s[tid];
  if (tid == 255) part[blockIdx.x] = s[255];
}

__global__ void k_scan2(int* __restrict__ part, int nb) {
  __shared__ int s[512];
  int t = threadIdx.x;
  if (nb <= 512) {
    int v = (t < nb) ? part[t] : 0;
    s[t] = v; __syncthreads();
    for (int o = 1; o < 512; o <<= 1) {
      int u = (t >= o) ? s[t - o] : 0;
      __syncthreads();
      s[t] += u;
      __syncthreads();
    }
    if (t < nb) part[t] = s[t] - v;
  } else if (t == 0) {
    int run = 0;
    for (int i = 0; i < nb; i++) { int x = part[i]; part[i] = run; run += x; }
  }
}

__global__ void k_scan3(const int* __restrict__ deg, const int* __restrict__ incl,
                        const int* __restrict__ part, int N, int E, int* __restrict__ off2) {
  int i = blockIdx.x * blockDim.x + threadIdx.x;
  if (i < N) off2[i] = part[i >> 8] + incl[i] - deg[i];
  if (i == 0) off2[N] = E;
}

__global__ void k_copyi(const int* __restrict__ a, int* __restrict__ b, int n) {
  int i = blockIdx.x * blockDim.x + threadIdx.x;
  if (i < n) b[i] = a[i];
}

__global__ void k_fill(const int* __restrict__ dst, int E,
                       int* __restrict__ cur, int* __restrict__ eix) {
  int e = blockIdx.x * blockDim.x + threadIdx.x;
  if (e >= E) return;
  int p = atomicAdd(&cur[dst[e]], 1);
  eix[p] = e;
}

// ---------------- hl / tacc ----------------
template<bool FIRST>
__global__ void k_hl(const float* __restrict__ aemb, const int* __restrict__ x_idx,
                     const float* __restrict__ scale, const float* __restrict__ shift,
                     const int* __restrict__ batch, const float* __restrict__ vn,
                     const float* __restrict__ epsArr, int l,
                     float* pt, float* __restrict__ hl, int N)
{
  int i = blockIdx.x;
  int c = threadIdx.x;
  if (c >= EMBD) return;
  float x;
  if (FIRST) {
    x = aemb[(size_t)x_idx[i] * EMBD + c];
  } else {
    x = pt[(size_t)i * EMBD + c];
    x = fmaxf(fmaf(x, scale[c], shift[c]), 0.f);
  }
  float h = x + vn[(size_t)batch[i] * EMBD + c];
  hl[(size_t)i * EMBD + c] = h;
  pt[(size_t)i * EMBD + c] = (1.f + epsArr[l]) * h;
}

// ---------------- CSR gather (2-edge ILP, XCD-aware bijective swizzle) ----------------
__global__ void k_gather(const int* __restrict__ off2, const int* __restrict__ eix,
                         const int* __restrict__ src, const int* __restrict__ eattr,
                         const float* __restrict__ hl, const float* __restrict__ bond,
                         float* __restrict__ tacc, int N)
{
  int bid = blockIdx.x;
  int nwg = gridDim.x;
  int q = nwg >> 3, r = nwg & 7;
  int xcd = bid & 7, idx = bid >> 3;
  int swz = (xcd < r ? xcd * (q + 1) : r * (q + 1) + (xcd - r) * q) + idx;
  int node = swz * 4 + (threadIdx.x >> 6);
  int lane = threadIdx.x & 63;
  if (node >= N) return;
  int p0 = off2[node], p1 = off2[node + 1];
  if (p0 == p1) return;
  float acc[5] = {0.f, 0.f, 0.f, 0.f, 0.f};
  int p = p0;
  for (; p + 1 < p1; p += 2) {
    int eA = eix[p], eB = eix[p + 1];
    int sA = src[eA], aA = eattr[eA];
    int sB = src[eB], aB = eattr[eB];
    const float* hA = hl + (size_t)sA * EMBD;
    const float* bA = bond + (size_t)aA * EMBD;
    const float* hB = hl + (size_t)sB * EMBD;
    const float* bB = bond + (size_t)aB * EMBD;
    #pragma unroll
    for (int qq = 0; qq < 5; qq++) {
      int c = lane + qq * 64;
      if (c < EMBD) {
        acc[qq] += fmaxf(hA[c] + bA[c], 0.f);
        acc[qq] += fmaxf(hB[c] + bB[c], 0.f);
      }
    }
  }
  if (p < p1) {
    int e = eix[p];
    int s = src[e], a = eattr[e];
    const float* hr = hl + (size_t)s * EMBD;
    const float* br = bond + (size_t)a * EMBD;
    #pragma unroll
    for (int qq = 0; qq < 5; qq++) {
      int c = lane + qq * 64;
      if (c < EMBD) acc[qq] += fmaxf(hr[c] + br[c], 0.f);
    }
  }
  float* tr = tacc + (size_t)node * EMBD;
  #pragma unroll
  for (int qq = 0; qq < 5; qq++) {
    int c = lane + qq * 64;
    if (c < EMBD) tr[c] += acc[qq];
  }
}

// ---------------- W split: [K][M] fp32 -> 3 bf16 planes [M][Kpad] ----------------
__global__ void k_splitW(const float* __restrict__ W, int K, int Kpad, int M,
                         short* __restrict__ planes)
{
  int idx = blockIdx.x * 256 + threadIdx.x;
  if (idx >= M * Kpad) return;
  int m = idx / Kpad, k = idx - m * Kpad;
  float x = (k < K) ? W[(size_t)k * M + m] : 0.f;
  short h1, h2, h3; split3(x, h1, h2, h3);
  size_t ps = (size_t)M * Kpad;
  planes[idx] = h1; planes[ps + idx] = h2; planes[2 * ps + idx] = h3;
}

// ---------------- split-bf16 MFMA GEMM, CT*64-col tiles; T14 prefetch (issue-early/write-late) ----------------
template<int CT, bool AFUSE>
__global__ __launch_bounds__(256) void k_mgemm(
    const float* __restrict__ A, const short* __restrict__ Wp,
    const float* __restrict__ bias, float* __restrict__ C,
    int n, int K, int Kpad, int M,
    const float* __restrict__ ascale, const float* __restrict__ ashift)
{
  __shared__ __align__(16) short lsA[3][64][40];
  __shared__ __align__(16) short lsB[3][CT * 64][40];
  int tid = threadIdx.x;
  int row0 = blockIdx.x * 64;
  int col0 = blockIdx.y * (CT * 64);
  int l = tid & 63, wid = tid >> 6;
  int wr = wid >> 1, wc = wid & 1;
  int lr = l & 15, kb = (l >> 4) * 8, rbase = (l >> 4) * 4;
  int sar = tid >> 2;
  int sak = (tid & 3) * 8;
  size_t planeSz = (size_t)M * Kpad;
  int nt = Kpad / 32;

  auto loadA = [&](int t, float x[8]) {
    int gr = row0 + sar;
    int kbase = t * 32 + sak;
    if (gr < n && kbase + 7 < K) {
      const float* ap = A + (size_t)gr * K + kbase;
      float4 u0 = *reinterpret_cast<const float4*>(ap);
      float4 u1 = *reinterpret_cast<const float4*>(ap + 4);
      x[0] = u0.x; x[1] = u0.y; x[2] = u0.z; x[3] = u0.w;
      x[4] = u1.x; x[5] = u1.y; x[6] = u1.z; x[7] = u1.w;
      if (AFUSE) {
        float4 sc0 = *reinterpret_cast<const float4*>(ascale + kbase);
        float4 sc1 = *reinterpret_cast<const float4*>(ascale + kbase + 4);
        float4 sf0 = *reinterpret_cast<const float4*>(ashift + kbase);
        float4 sf1 = *reinterpret_cast<const float4*>(ashift + kbase + 4);
        x[0] = fmaxf(fmaf(x[0], sc0.x, sf0.x), 0.f);
        x[1] = fmaxf(fmaf(x[1], sc0.y, sf0.y), 0.f);
        x[2] = fmaxf(fmaf(x[2], sc0.z, sf0.z), 0.f);
        x[3] = fmaxf(fmaf(x[3], sc0.w, sf0.w), 0.f);
        x[4] = fmaxf(fmaf(x[4], sc1.x, sf1.x), 0.f);
        x[5] = fmaxf(fmaf(x[5], sc1.y, sf1.y), 0.f);
        x[6] = fmaxf(fmaf(x[6], sc1.z, sf1.z), 0.f);
        x[7] = fmaxf(fmaf(x[7], sc1.w, sf1.w), 0.f);
      }
    } else {
      #pragma unroll
      for (int j = 0; j < 8; j++) {
        int k = kbase + j;
        float v = 0.f;
        if (gr < n && k < K) {
          v = A[(size_t)gr * K + k];
          if (AFUSE) v = fmaxf(fmaf(v, ascale[k], ashift[k]), 0.f);
        }
        x[j] = v;
      }
    }
  };

  auto loadB = [&](int t, short8v v0[3], short8v v1[3]) {
    int k0 = t * 32;
    if constexpr (CT == 2) {
      int sbc = tid >> 1;
      int sbk = (tid & 1) * 16;
      int gc = col0 + sbc;
      #pragma unroll
      for (int p = 0; p < 3; p++) {
        if (gc < M) {
          const short* bp = Wp + (size_t)p * planeSz + (size_t)gc * Kpad + k0 + sbk;
          v0[p] = *reinterpret_cast<const short8v*>(bp);
          v1[p] = *reinterpret_cast<const short8v*>(bp + 8);
        } else {
          #pragma unroll
          for (int j = 0; j < 8; j++) { v0[p][j] = 0; v1[p][j] = 0; }
        }
      }
    } else {
      int sbc = tid >> 2;
      int sbk = (tid & 3) * 8;
      int gc = col0 + sbc;
      #pragma unroll
      for (int p = 0; p < 3; p++) {
        if (gc < M) {
          const short* bp = Wp + (size_t)p * planeSz + (size_t)gc * Kpad + k0 + sbk;
          v0[p] = *reinterpret_cast<const short8v*>(bp);
        } else {
          #pragma unroll
          for (int j = 0; j < 8; j++) v0[p][j] = 0;
        }
        (void)v1;
      }
    }
  };

  f32x4 acc[2][CT * 2];
  #pragma unroll
  for (int i = 0; i < 2; i++)
    #pragma unroll
    for (int j = 0; j < CT * 2; j++) acc[i][j] = (f32x4){0.f, 0.f, 0.f, 0.f};

  float xc[8];
  short8v b0c[3], b1c[3];
  loadA(0, xc);
  loadB(0, b0c, b1c);

  for (int t = 0; t < nt; t++) {
    // ---- write phase: split current A regs -> LDS; write current B regs -> LDS ----
    {
      uint4 q1, q2, q3;
      unsigned* p1 = (unsigned*)&q1; unsigned* p2 = (unsigned*)&q2; unsigned* p3 = (unsigned*)&q3;
      #pragma unroll
      for (int j = 0; j < 4; j++) split3_pair(xc[2 * j], xc[2 * j + 1], p1[j], p2[j], p3[j]);
      *reinterpret_cast<uint4*>(&lsA[0][sar][sak]) = q1;
      *reinterpret_cast<uint4*>(&lsA[1][sar][sak]) = q2;
      *reinterpret_cast<uint4*>(&lsA[2][sar][sak]) = q3;
    }
    if constexpr (CT == 2) {
      int sbc = tid >> 1;
      int sbk = (tid & 1) * 16;
      #pragma unroll
      for (int p = 0; p < 3; p++) {
        *reinterpret_cast<short8v*>(&lsB[p][sbc][sbk]) = b0c[p];
        *reinterpret_cast<short8v*>(&lsB[p][sbc][sbk + 8]) = b1c[p];
      }
    } else {
      int sbc = tid >> 2;
      int sbk = (tid & 3) * 8;
      #pragma unroll
      for (int p = 0; p < 3; p++)
        *reinterpret_cast<short8v*>(&lsB[p][sbc][sbk]) = b0c[p];
    }
    __syncthreads();

    // ---- issue next tile's global loads (latency hides under MFMA below) ----
    float xn[8];
    short8v b0n[3], b1n[3];
    bool more = (t + 1 < nt);
    if (more) { loadA(t + 1, xn); loadB(t + 1, b0n, b1n); }

    // ---- compute ----
    short8v fa[3][2];
    #pragma unroll
    for (int p = 0; p < 3; p++)
      #pragma unroll
      for (int rf = 0; rf < 2; rf++)
        fa[p][rf] = *reinterpret_cast<const short8v*>(&lsA[p][wr * 32 + rf * 16 + lr][kb]);
    #pragma unroll
    for (int cf = 0; cf < CT * 2; cf++) {
      int bcol = wc * (CT * 32) + cf * 16 + lr;
      short8v fb0 = *reinterpret_cast<const short8v*>(&lsB[0][bcol][kb]);
      short8v fb1 = *reinterpret_cast<const short8v*>(&lsB[1][bcol][kb]);
      short8v fb2 = *reinterpret_cast<const short8v*>(&lsB[2][bcol][kb]);
      #pragma unroll
      for (int rf = 0; rf < 2; rf++) {
        f32x4 a = acc[rf][cf];
        a = __builtin_amdgcn_mfma_f32_16x16x32_bf16(fa[0][rf], fb0, a, 0, 0, 0);
        a = __builtin_amdgcn_mfma_f32_16x16x32_bf16(fa[0][rf], fb1, a, 0, 0, 0);
        a = __builtin_amdgcn_mfma_f32_16x16x32_bf16(fa[1][rf], fb0, a, 0, 0, 0);
        a = __builtin_amdgcn_mfma_f32_16x16x32_bf16(fa[1][rf], fb1, a, 0, 0, 0);
        a = __builtin_amdgcn_mfma_f32_16x16x32_bf16(fa[0][rf], fb2, a, 0, 0, 0);
        a = __builtin_amdgcn_mfma_f32_16x16x32_bf16(fa[2][rf], fb0, a, 0, 0, 0);
        acc[rf][cf] = a;
      }
    }
    __syncthreads();

    if (more) {
      #pragma unroll
      for (int j = 0; j < 8; j++) xc[j] = xn[j];
      #pragma unroll
      for (int p = 0; p < 3; p++) { b0c[p] = b0n[p]; b1c[p] = b1n[p]; }
    }
  }

  #pragma unroll
  for (int rf = 0; rf < 2; rf++) {
    #pragma unroll
    for (int cf = 0; cf < CT * 2; cf++) {
      int col = col0 + wc * (CT * 32) + cf * 16 + lr;
      if (col >= M) continue;
      float bv = bias[col];
      #pragma unroll
      for (int r = 0; r < 4; r++) {
        int row = row0 + wr * 32 + rf * 16 + rbase + r;
        if (row < n) C[(size_t)row * M + col] = acc[rf][cf][r] + bv;
      }
    }
  }
}

// ---------------- MFMA Gram ----------------
__global__ __launch_bounds__(256) void k_mgram(const float* __restrict__ A, int N,
                                               double* __restrict__ gpart)
{
  int bx = blockIdx.x;
  int ti = 0;
  {
    const int o1 = 5, o2 = 9, o3 = 12, o4 = 14;
    if (bx >= o1) ti = 1;
    if (bx >= o2) ti = 2;
    if (bx >= o3) ti = 3;
    if (bx >= o4) ti = 4;
  }
  const int offs[5] = {0, 5, 9, 12, 14};
  int tj = ti + (bx - offs[ti]);
  int I = ti * 64, J = tj * 64;
  __shared__ __align__(16) short lsI[3][64][40];
  __shared__ __align__(16) short lsJ[3][64][40];
  int tid = threadIdx.x;
  int l = tid & 63, wid = tid >> 6;
  int wr = wid >> 1, wc = wid & 1;
  int lr = l & 15, kb = (l >> 4) * 8, rbase = (l >> 4) * 4;
  int sr = tid & 31;
  int sc0 = (tid >> 5) * 8;

  f32x4 acc[2][2];
  #pragma unroll
  for (int i = 0; i < 2; i++)
    #pragma unroll
    for (int j = 0; j < 2; j++) acc[i][j] = (f32x4){0.f, 0.f, 0.f, 0.f};

  for (int r0 = blockIdx.y * 32; r0 < N; r0 += gridDim.y * 32) {
    int gr = r0 + sr;
    float xi[8], xj[8];
    {
      int ci = I + sc0;
      if (gr < N && ci + 7 < EMBD) {
        const float* ap = A + (size_t)gr * EMBD + ci;
        float4 u0 = *reinterpret_cast<const float4*>(ap);
        float4 u1 = *reinterpret_cast<const float4*>(ap + 4);
        xi[0] = u0.x; xi[1] = u0.y; xi[2] = u0.z; xi[3] = u0.w;
        xi[4] = u1.x; xi[5] = u1.y; xi[6] = u1.z; xi[7] = u1.w;
      } else {
        #pragma unroll
        for (int j = 0; j < 8; j++) {
          int c = ci + j;
          xi[j] = (gr < N && c < EMBD) ? A[(size_t)gr * EMBD + c] : 0.f;
        }
      }
      int cj = J + sc0;
      if (gr < N && cj + 7 < EMBD) {
        const float* ap = A + (size_t)gr * EMBD + cj;
        float4 u0 = *reinterpret_cast<const float4*>(ap);
        float4 u1 = *reinterpret_cast<const float4*>(ap + 4);
        xj[0] = u0.x; xj[1] = u0.y; xj[2] = u0.z; xj[3] = u0.w;
        xj[4] = u1.x; xj[5] = u1.y; xj[6] = u1.z; xj[7] = u1.w;
      } else {
        #pragma unroll
        for (int j = 0; j < 8; j++) {
          int c = cj + j;
          xj[j] = (gr < N && c < EMBD) ? A[(size_t)gr * EMBD + c] : 0.f;
        }
      }
    }
    #pragma unroll
    for (int j = 0; j < 8; j++) {
      short a1, a2, a3; split3(xi[j], a1, a2, a3);
      lsI[0][sc0 + j][sr] = a1; lsI[1][sc0 + j][sr] = a2; lsI[2][sc0 + j][sr] = a3;
      short b1, b2, b3; split3(xj[j], b1, b2, b3);
      lsJ[0][sc0 + j][sr] = b1; lsJ[1][sc0 + j][sr] = b2; lsJ[2][sc0 + j][sr] = b3;
    }
    __syncthreads();
    short8v fa[3][2];
    #pragma unroll
    for (int p = 0; p < 3; p++)
      #pragma unroll
      for (int rf = 0; rf < 2; rf++)
        fa[p][rf] = *reinterpret_cast<const short8v*>(&lsI[p][wr * 32 + rf * 16 + lr][kb]);
    #pragma unroll
    for (int cf = 0; cf < 2; cf++) {
      int bcol = wc * 32 + cf * 16 + lr;
      short8v fb0 = *reinterpret_cast<const short8v*>(&lsJ[0][bcol][kb]);
      short8v fb1 = *reinterpret_cast<const short8v*>(&lsJ[1][bcol][kb]);
      short8v fb2 = *reinterpret_cast<const short8v*>(&lsJ[2][bcol][kb]);
      #pragma unroll
      for (int rf = 0; rf < 2; rf++) {
        f32x4 a = acc[rf][cf];
        a = __builtin_amdgcn_mfma_f32_16x16x32_bf16(fa[0][rf], fb0, a, 0, 0, 0);
        a = __builtin_amdgcn_mfma_f32_16x16x32_bf16(fa[0][rf], fb1, a, 0, 0, 0);
        a = __builtin_amdgcn_mfma_f32_16x16x32_bf16(fa[1][rf], fb0, a, 0, 0, 0);
        a = __builtin_amdgcn_mfma_f32_16x16x32_bf16(fa[1][rf], fb1, a, 0, 0, 0);
        a = __builtin_amdgcn_mfma_f32_16x16x32_bf16(fa[0][rf], fb2, a, 0, 0, 0);
        a = __builtin_amdgcn_mfma_f32_16x16x32_bf16(fa[2][rf], fb0, a, 0, 0, 0);
        acc[rf][cf] = a;
      }
    }
    __syncthreads();
  }
  size_t base = ((size_t)blockIdx.y * 15 + bx) * 4096;
  #pragma unroll
  for (int rf = 0; rf < 2; rf++)
    #pragma unroll
    for (int cf = 0; cf < 2; cf++) {
      int col = wc * 32 + cf * 16 + lr;
      #pragma unroll
      for (int r = 0; r < 4; r++) {
        int row = wr * 32 + rf * 16 + rbase + r;
        gpart[base + (size_t)row * 64 + col] = (double)acc[rf][cf][r];
      }
    }
}

// ---------------- 64x64 fp32 GEMM (vn path / head) ----------------
template<bool AFUSE, bool ORELU>
__global__ __launch_bounds__(256) void k_gemm(
    const float* __restrict__ A, const float* __restrict__ W,
    const float* __restrict__ bias, float* __restrict__ C,
    int N, int K, int M,
    const float* __restrict__ ascale, const float* __restrict__ ashift)
{
  __shared__ __align__(16) float As[16][72];
  __shared__ __align__(16) float Bs[16][72];
  int tid = threadIdx.x;
  int row0 = blockIdx.x * 64;
  int col0 = blockIdx.y * 64;
  int tx = tid & 15, ty = tid >> 4;
  bool kvec = ((K & 3) == 0);
  bool mvec = ((M & 3) == 0);
  float acc[4][4] = {};
  for (int k0 = 0; k0 < K; k0 += 16) {
    {
      int r = tid >> 2;
      int kq = (tid & 3) * 4;
      int gr = row0 + r;
      float a0 = 0.f, a1 = 0.f, a2 = 0.f, a3 = 0.f;
      if (gr < N) {
        const float* ap = A + (size_t)gr * K + k0 + kq;
        int k = k0 + kq;
        if (kvec && k + 3 < K) {
          float4 t = *reinterpret_cast<const float4*>(ap);
          a0 = t.x; a1 = t.y; a2 = t.z; a3 = t.w;
        } else {
          if (k + 0 < K) a0 = ap[0];
          if (k + 1 < K) a1 = ap[1];
          if (k + 2 < K) a2 = ap[2];
          if (k + 3 < K) a3 = ap[3];
        }
        if (AFUSE) {
          if (k + 0 < K) a0 = fmaxf(fmaf(a0, ascale[k + 0], ashift[k + 0]), 0.f);
          if (k + 1 < K) a1 = fmaxf(fmaf(a1, ascale[k + 1], ashift[k + 1]), 0.f);
          if (k + 2 < K) a2 = fmaxf(fmaf(a2, ascale[k + 2], ashift[k + 2]), 0.f);
          if (k + 3 < K) a3 = fmaxf(fmaf(a3, ascale[k + 3], ashift[k + 3]), 0.f);
        }
      }
      As[kq + 0][r] = a0; As[kq + 1][r] = a1; As[kq + 2][r] = a2; As[kq + 3][r] = a3;
    }
    {
      int kk = tid >> 4;
      int j = (tid & 15) * 4;
      int gk = k0 + kk;
      float4 bv = {0.f, 0.f, 0.f, 0.f};
      if (gk < K) {
        const float* wp = W + (size_t)gk * M + col0 + j;
        if (mvec && col0 + j + 3 < M) {
          bv = *reinterpret_cast<const float4*>(wp);
        } else {
          if (col0 + j + 0 < M) bv.x = wp[0];
          if (col0 + j + 1 < M) bv.y = wp[1];
          if (col0 + j + 2 < M) bv.z = wp[2];
          if (col0 + j + 3 < M) bv.w = wp[3];
        }
      }
      *reinterpret_cast<float4*>(&Bs[kk][j]) = bv;
    }
    __syncthreads();
    #pragma unroll
    for (int kk = 0; kk < 16; kk++) {
      float4 a4 = *reinterpret_cast<const float4*>(&As[kk][ty * 4]);
      float4 b4 = *reinterpret_cast<const float4*>(&Bs[kk][tx * 4]);
      float a[4] = {a4.x, a4.y, a4.z, a4.w};
      float b[4] = {b4.x, b4.y, b4.z, b4.w};
      #pragma unroll
      for (int u = 0; u < 4; u++)
        #pragma unroll
        for (int v = 0; v < 4; v++)
          acc[u][v] = fmaf(a[u], b[v], acc[u][v]);
    }
    __syncthreads();
  }
  float bv[4];
  #pragma unroll
  for (int v = 0; v < 4; v++) { int gc = col0 + tx * 4 + v; bv[v] = (gc < M) ? bias[gc] : 0.f; }
  #pragma unroll
  for (int u = 0; u < 4; u++) {
    int gr = row0 + ty * 4 + u;
    if (gr >= N) continue;
    int gc0 = col0 + tx * 4;
    float val[4];
    #pragma unroll
    for (int v = 0; v < 4; v++) {
      float x = acc[u][v] + bv[v];
      if (ORELU) x = fmaxf(x, 0.f);
      val[v] = x;
    }
    if (mvec && gc0 + 3 < M) {
      float4 o = {val[0], val[1], val[2], val[3]};
      *reinterpret_cast<float4*>(C + (size_t)gr * M + gc0) = o;
    } else {
      #pragma unroll
      for (int v = 0; v < 4; v++) {
        int gc = gc0 + v;
        if (gc < M) C[(size_t)gr * M + gc] = val[v];
      }
    }
  }
}

__global__ void k_gramfin(const double* __restrict__ gpart, double* __restrict__ G)
{
  int e = blockIdx.x * 256 + threadIdx.x;
  if (e >= 15 * 4096) return;
  int tile = e >> 12;
  int ii = (e >> 6) & 63, jj = e & 63;
  const int tit[15] = {0,0,0,0,0,1,1,1,1,2,2,2,3,3,4};
  const int tjt[15] = {0,1,2,3,4,1,2,3,4,2,3,4,3,4,4};
  int gi = tit[tile] * 64 + ii, gj = tjt[tile] * 64 + jj;
  if (gi >= EMBD || gj >= EMBD) return;
  double s = 0.0;
  for (int kb = 0; kb < GRAM_KB; kb++)
    s += gpart[((size_t)kb * 15 + tile) * 4096 + ii * 64 + jj];
  G[(size_t)gi * EMBD + gj] = s;
  G[(size_t)gj * EMBD + gi] = s;
}

__global__ void k_bn1gram(const double* __restrict__ G, const double* __restrict__ cbuf,
                          const float* __restrict__ W1, const float* __restrict__ b1,
                          const float* __restrict__ g, const float* __restrict__ b,
                          int n, float* __restrict__ sc, float* __restrict__ sh)
{
  int j = blockIdx.x;
  int t = threadIdx.x;
  __shared__ double ws[EMBD];
  __shared__ double red[256];
  for (int k = t; k < EMBD; k += 256) ws[k] = (double)W1[(size_t)k * 600 + j];
  __syncthreads();
  int i1 = 256 + t;
  double y0 = 0.0, y1 = 0.0;
  for (int k = 0; k < EMBD; k++) {
    double wk = ws[k];
    y0 += G[(size_t)k * EMBD + t] * wk;
    if (i1 < EMBD) y1 += G[(size_t)k * EMBD + i1] * wk;
  }
  double part = ws[t] * y0 + ((i1 < EMBD) ? ws[i1] * y1 : 0.0);
  double dpart = cbuf[t] * ws[t] + ((i1 < EMBD) ? cbuf[i1] * ws[i1] : 0.0);
  red[t] = part; __syncthreads();
  for (int w = 128; w > 0; w >>= 1) { if (t < w) red[t] += red[t + w]; __syncthreads(); }
  double Q = red[0]; __syncthreads();
  red[t] = dpart; __syncthreads();
  for (int w = 128; w > 0; w >>= 1) { if (t < w) red[t] += red[t + w]; __syncthreads(); }
  if (t == 0) {
    double d = red[0];
    double bj = (double)b1[j];
    double S = d + (double)n * bj;
    double Qf = Q + 2.0 * bj * d + (double)n * bj * bj;
    double m = S / n;
    double var = Qf / n - m * m;
    double inv = 1.0 / sqrt(var + 1e-5);
    double scv = (double)g[j] * inv;
    sc[j] = (float)scv;
    sh[j] = (float)((double)b[j] - m * scv);
  }
}

// ---------------- column stats ----------------
__global__ void k_colstats(const float* __restrict__ X, int n, int C,
                           double* __restrict__ psum, double* __restrict__ psq)
{
  int tid = threadIdx.x;
  int col = blockIdx.x * 64 + (tid & 63);
  int rl = tid >> 6;
  double s = 0.0, q = 0.0;
  if (col < C) {
    int stride = gridDim.y * 4;
    for (int r = blockIdx.y * 4 + rl; r < n; r += stride) {
      double x = (double)X[(size_t)r * C + col];
      s += x; q += x * x;
    }
  }
  __shared__ double ls[2][4][64];
  ls[0][rl][tid & 63] = s;
  ls[1][rl][tid & 63] = q;
  __syncthreads();
  if (rl == 0 && col < C) {
    int c = tid & 63;
    double S = ls[0][0][c] + ls[0][1][c] + ls[0][2][c] + ls[0][3][c];
    double Q = ls[1][0][c] + ls[1][1][c] + ls[1][2][c] + ls[1][3][c];
    psum[(size_t)blockIdx.y * C + col] = S;
    psq [(size_t)blockIdx.y * C + col] = Q;
  }
}

__global__ void k_redcol(const double* __restrict__ psum, int R, int C, double* __restrict__ cbuf)
{
  int c = blockIdx.x * blockDim.x + threadIdx.x;
  if (c >= C) return;
  double s = 0.0;
  for (int r = 0; r < R; r++) s += psum[(size_t)r * C + c];
  cbuf[c] = s;
}

__global__ void k_finstats(const double* __restrict__ psum, const double* __restrict__ psq,
                           int R, int M, int n,
                           const float* __restrict__ g, const float* __restrict__ b,
                           float* __restrict__ sc, float* __restrict__ sh)
{
  int j = blockIdx.x;
  int t = threadIdx.x;
  double s = 0.0, q = 0.0;
  for (int r = t; r < R; r += 256) { s += psum[(size_t)r * M + j]; q += psq[(size_t)r * M + j]; }
  __shared__ double ls[256], lq[256];
  ls[t] = s; lq[t] = q; __syncthreads();
  for (int w = 128; w > 0; w >>= 1) {
    if (t < w) { ls[t] += ls[t + w]; lq[t] += lq[t + w]; }
    __syncthreads();
  }
  if (t == 0) {
    double m = ls[0] / n;
    double v = lq[0] / n - m * m;
    double inv = 1.0 / sqrt(v + 1e-5);
    double scv = (double)g[j] * inv;
    sc[j] = (float)scv;
    sh[j] = (float)((double)b[j] - m * scv);
  }
}

// ---------------- vn / pool / sem ----------------
__global__ void k_vnseg(const float* __restrict__ hl, const int* __restrict__ off,
                        const float* __restrict__ vn, float* __restrict__ vtmp)
{
  int g = blockIdx.x;
  int c = threadIdx.x;
  if (c >= EMBD) return;
  int r0 = off[g], r1 = off[g + 1];
  float s = 0.f;
  for (int r = r0; r < r1; r++) s += hl[(size_t)r * EMBD + c];
  vtmp[(size_t)g * EMBD + c] = s + vn[(size_t)g * EMBD + c];
}

__global__ void k_vnfinal(const float* __restrict__ vnraw, const float* __restrict__ scale,
                          const float* __restrict__ shift, float* __restrict__ vn, int total)
{
  int i = blockIdx.x * blockDim.x + threadIdx.x;
  if (i >= total) return;
  int c = i % EMBD;
  vn[i] = fmaxf(fmaf(vnraw[i], scale[c], shift[c]), 0.f);
}

__global__ void k_pool(const float* __restrict__ t2, const int* __restrict__ off,
                       const float* __restrict__ scale, const float* __restrict__ shift,
                       float* __restrict__ hg)
{
  int g = blockIdx.x;
  int c = threadIdx.x;
  if (c >= EMBD) return;
  int r0 = off[g], r1 = off[g + 1];
  float s = 0.f;
  for (int r = r0; r < r1; r++) s += t2[(size_t)r * EMBD + c];
  int cnt = r1 - r0;
  float denom = (cnt > 0) ? (float)cnt : 1.f;
  hg[(size_t)g * EMBD + c] = (scale[c] * s + shift[c] * (float)cnt) / denom;
}

__global__ void k_sem(const float* __restrict__ logits, const float* __restrict__ gum,
                      const float* __restrict__ selW, const float* __restrict__ selb,
                      float* __restrict__ msgw)
{
  int idx = blockIdx.x * blockDim.x + threadIdx.x;
  if (idx >= GNUM * LSEM) return;
  int g = idx / LSEM, l = idx % LSEM;
  const float* lp = logits + (size_t)g * (LSEM * VSEM) + l * VSEM;
  const float* gp = gum + (size_t)g * (LSEM * VSEM) + l * VSEM;
  float best = -1e30f; int bi = 0;
  for (int v = 0; v < VSEM; v++) {
    float y = lp[v] + gp[v];
    if (y > best) { best = y; bi = v; }
  }
  float* o = msgw + (size_t)g * (3 * LSEM) + l * 3;
  o[0] = selW[bi * 3 + 0] + selb[0];
  o[1] = selW[bi * 3 + 1] + selb[1];
  o[2] = selW[bi * 3 + 2] + selb[2];
}

// ---------------- host ----------------
template<bool AFUSE, bool ORELU>
static void gemm(const float* A, const float* W, const float* b, float* C,
                 int n, int k, int m, const float* sc, const float* sh, hipStream_t st)
{
  dim3 grid((n + 63) / 64, (m + 63) / 64);
  k_gemm<AFUSE, ORELU><<<grid, 256, 0, st>>>(A, W, b, C, n, k, m, sc, sh);
}

extern "C" void kernel_launch(void* const* d_in, const int* in_sizes, int n_in,
                              void* d_out, int out_size, void* d_ws, size_t ws_size,
                              hipStream_t stream)
{
  const int*   x_idx     = (const int*)d_in[0];
  const int*   eidx      = (const int*)d_in[1];
  const int*   eattr     = (const int*)d_in[2];
  const int*   batch     = (const int*)d_in[3];
  const float* gumbel    = (const float*)d_in[4];
  const float* atom_emb  = (const float*)d_in[5];
  const float* bond_emb  = (const float*)d_in[6];
  const float* eps       = (const float*)d_in[7];
  const float* gin_W1    = (const float*)d_in[8];
  const float* gin_b1    = (const float*)d_in[9];
  const float* gin_bn1_g = (const float*)d_in[10];
  const float* gin_bn1_b = (const float*)d_in[11];
  const float* gin_W2    = (const float*)d_in[12];
  const float* gin_b2    = (const float*)d_in[13];
  const float* node_bn_g = (const float*)d_in[14];
  const float* node_bn_b = (const float*)d_in[15];
  const float* vn_W1     = (const float*)d_in[16];
  const float* vn_b1     = (const float*)d_in[17];
  const float* vn_bn1_g  = (const float*)d_in[18];
  const float* vn_bn1_b  = (const float*)d_in[19];
  const float* vn_W2     = (const float*)d_in[20];
  const float* vn_b2     = (const float*)d_in[21];
  const float* vn_bn2_g  = (const float*)d_in[22];
  const float* vn_bn2_b  = (const float*)d_in[23];
  const float* pre_W     = (const float*)d_in[24];
  const float* pre_b     = (const float*)d_in[25];
  const float* sel_W     = (const float*)d_in[26];
  const float* sel_b     = (const float*)d_in[27];
  const float* aft_W     = (const float*)d_in[28];
  const float* aft_b     = (const float*)d_in[29];
  const float* hW1       = (const float*)d_in[30];
  const float* hb1       = (const float*)d_in[31];
  const float* hW2       = (const float*)d_in[32];
  const float* hb2       = (const float*)d_in[33];
  const float* hW3       = (const float*)d_in[34];
  const float* hb3       = (const float*)d_in[35];

  const int N = in_sizes[0];
  const int E = in_sizes[2];
  const int RB = 128;
  float* out = (float*)d_out;
  (void)n_in;

  char* ws = (char*)d_ws;
  size_t pos = 0;
  auto alloc = [&](size_t bytes) -> char* {
    char* p = ws + pos;
    pos = (pos + bytes + 255) & ~(size_t)255;
    return p;
  };
  int*    off   = (int*)   alloc((GNUM + 1) * sizeof(int));
  float*  hbuf0 = (float*) alloc((size_t)N * EMBD * 4);
  float*  hbuf1 = (float*) alloc((size_t)N * EMBD * 4);
  double* psum  = (double*)alloc((size_t)RB * 600 * 8);
  double* psq   = (double*)alloc((size_t)RB * 600 * 8);
  float*  vn    = (float*) alloc((size_t)GNUM * EMBD * 4);
  float*  vtmp  = (float*) alloc((size_t)GNUM * EMBD * 4);
  float*  vnraw = (float*) alloc((size_t)GNUM * EMBD * 4);
  double* cbuf  = (double*)alloc(EMBD * 8);
  int*    off2  = (int*)   alloc((size_t)(N + 1) * 4);
  int*    eix   = (int*)   alloc((size_t)E * 4);
  short*  wsplit1 = (short*)alloc((size_t)600 * 320 * 3 * 2);
  short*  wsplit2 = (short*)alloc((size_t)300 * 608 * 3 * 2);
  float*  s1    = (float*) alloc(600 * 4);
  float*  sh1   = (float*) alloc(600 * 4);
  float*  s2    = (float*) alloc(EMBD * 4);
  float*  sh2   = (float*) alloc(EMBD * 4);
  float*  vs1   = (float*) alloc(600 * 4);
  float*  vsh1  = (float*) alloc(600 * 4);
  float*  vs2   = (float*) alloc(EMBD * 4);
  float*  vsh2  = (float*) alloc(EMBD * 4);

  const size_t gpartBytes = (size_t)GRAM_KB * 15 * 4096 * 8;
  const size_t gBytes     = (size_t)EMBD * EMBD * 8;
  const size_t csrScratch = (size_t)N * 4 * 3 + 4096;
  const long long CH_MIN  = 2048;
  size_t slack = 1u << 20;
  size_t region_need = gpartBytes + gBytes;
  if (region_need < csrScratch) region_need = csrScratch;
  size_t t1_min = (size_t)CH_MIN * 600 * 4;
  if (region_need < t1_min) region_need = t1_min;

  if (ws_size < pos + region_need + slack) {
    float v = 1000.f + (float)(ws_size >> 20);
    k_diag<<<(out_size + 255) / 256, 256, 0, stream>>>(out, out_size, v);
    return;
  }

  size_t regionBytes = ws_size - pos - slack;
  char* region = ws + pos;
  int* deg  = (int*)region;
  int* incl = (int*)(region + (size_t)N * 4);
  int* cur  = (int*)(region + (size_t)N * 8);
  int* part = (int*)(region + (size_t)N * 12);
  double* gpart = (double*)region;
  double* G     = (double*)(region + gpartBytes);
  float*  t1buf = (float*)region;
  int CH;
  {
    long long ch = (long long)(regionBytes / (600ull * 4ull));
    if (ch > 32768) ch = 32768;
    ch &= ~63LL;
    if (ch < CH_MIN) ch = CH_MIN;
    long long npad = ((long long)N + 63) & ~63LL;
    if (ch > npad && npad >= CH_MIN) ch = npad;
    CH = (int)ch;
  }
  float* v1 = t1buf;
  float* hg     = vnraw;
  float* logits = t1buf;
  float* msgw   = t1buf + (size_t)GNUM * EMBD;
  float* dis    = vtmp;
  float* o1     = vn;
  float* o2     = vn + (size_t)GNUM * 128;

  k_zero<<<(GNUM * EMBD + 255) / 256, 256, 0, stream>>>(vn, GNUM * EMBD);
  k_offsets<<<(GNUM + 1 + 255) / 256, 256, 0, stream>>>(batch, N, off);

  const int* esrc = eidx;
  const int* edst = eidx + E;

  // CSR build (once)
  {
    int NB = (N + 255) / 256;
    k_seti<<<(N + 255) / 256, 256, 0, stream>>>(deg, N, 0);
    k_deg<<<(E + 255) / 256, 256, 0, stream>>>(edst, E, deg);
    k_scan1<<<NB, 256, 0, stream>>>(deg, N, incl, part);
    k_scan2<<<1, 512, 0, stream>>>(part, NB);
    k_scan3<<<(N + 255) / 256, 256, 0, stream>>>(deg, incl, part, N, E, off2);
    k_copyi<<<(N + 255) / 256, 256, 0, stream>>>(off2, cur, N);
    k_fill<<<(E + 255) / 256, 256, 0, stream>>>(edst, E, cur, eix);
  }

  float* hb[2] = {hbuf0, hbuf1};

  for (int l = 0; l < NLAY; l++) {
    float* tac = hb[l & 1];
    float* hlb = hb[(l + 1) & 1];

    if (l == 0)
      k_hl<true><<<N, 320, 0, stream>>>(atom_emb, x_idx, nullptr, nullptr, batch, vn, eps, l, tac, hlb, N);
    else
      k_hl<false><<<N, 320, 0, stream>>>(nullptr, nullptr, s2, sh2, batch, vn, eps, l, tac, hlb, N);

    k_gather<<<(N + 3) / 4, 256, 0, stream>>>(off2, eix, esrc, eattr, hlb,
                                              bond_emb + (size_t)l * 5 * EMBD, tac, N);

    if (l < NLAY - 1)
      k_vnseg<<<GNUM, 320, 0, stream>>>(hlb, off, vn, vtmp);

    // BN1 stats via Gram identity (MFMA gram)
    k_colstats<<<dim3(5, RB), 256, 0, stream>>>(tac, N, EMBD, psum, psq);
    k_redcol<<<2, 256, 0, stream>>>(psum, RB, EMBD, cbuf);
    k_mgram<<<dim3(15, GRAM_KB), 256, 0, stream>>>(tac, N, gpart);
    k_gramfin<<<240, 256, 0, stream>>>(gpart, G);
    k_bn1gram<<<600, 256, 0, stream>>>(G, cbuf, gin_W1 + (size_t)l * EMBD * 600,
                                       gin_b1 + (size_t)l * 600,
                                       gin_bn1_g + (size_t)l * 600, gin_bn1_b + (size_t)l * 600,
                                       N, s1, sh1);

    // pre-split weights into bf16 planes
    k_splitW<<<(600 * 320 + 255) / 256, 256, 0, stream>>>(gin_W1 + (size_t)l * EMBD * 600, 300, 320, 600, wsplit1);
    k_splitW<<<(300 * 608 + 255) / 256, 256, 0, stream>>>(gin_W2 + (size_t)l * 600 * EMBD, 600, 608, 300, wsplit2);

    // chunked split-MFMA GEMM1 (CT=2) -> t1buf -> GEMM2 (CT=1) -> h rows
    for (int r0 = 0; r0 < N; r0 += CH) {
      int nr = (N - r0 < CH) ? (N - r0) : CH;
      dim3 g1((nr + 63) / 64, 5);
      k_mgemm<2, false><<<g1, 256, 0, stream>>>(tac + (size_t)r0 * EMBD, wsplit1,
                                                gin_b1 + (size_t)l * 600, t1buf,
                                                nr, 300, 320, 600, nullptr, nullptr);
      dim3 g2((nr + 63) / 64, 5);
      k_mgemm<1, true><<<g2, 256, 0, stream>>>(t1buf, wsplit2,
                                               gin_b2 + (size_t)l * EMBD, hlb + (size_t)r0 * EMBD,
                                               nr, 600, 608, 300, s1, sh1);
    }
    k_colstats<<<dim3(5, RB), 256, 0, stream>>>(hlb, N, EMBD, psum, psq);
    k_finstats<<<EMBD, 256, 0, stream>>>(psum, psq, RB, EMBD, N,
                                         node_bn_g + (size_t)l * EMBD, node_bn_b + (size_t)l * EMBD, s2, sh2);

    if (l < NLAY - 1) {
      gemm<false, false>(vtmp, vn_W1 + (size_t)l * EMBD * 600, vn_b1 + (size_t)l * 600, v1,
                         GNUM, EMBD, 600, nullptr, nullptr, stream);
      k_colstats<<<dim3(10, RB), 256, 0, stream>>>(v1, GNUM, 600, psum, psq);
      k_finstats<<<600, 256, 0, stream>>>(psum, psq, RB, 600, GNUM,
                                          vn_bn1_g + (size_t)l * 600, vn_bn1_b + (size_t)l * 600, vs1, vsh1);
      gemm<true, false>(v1, vn_W2 + (size_t)l * 600 * EMBD, vn_b2 + (size_t)l * EMBD, vnraw,
                        GNUM, 600, EMBD, vs1, vsh1, stream);
      k_colstats<<<dim3(5, RB), 256, 0, stream>>>(vnraw, GNUM, EMBD, psum, psq);
      k_finstats<<<EMBD, 256, 0, stream>>>(psum, psq, RB, EMBD, GNUM,
                                           vn_bn2_g + (size_t)l * EMBD, vn_bn2_b + (size_t)l * EMBD, vs2, vsh2);
      k_vnfinal<<<(GNUM * EMBD + 255) / 256, 256, 0, stream>>>(vnraw, vs2, vsh2, vn, GNUM * EMBD);
    }
  }

  float* lastH = hb[NLAY & 1];
  k_pool<<<GNUM, 320, 0, stream>>>(lastH, off, s2, sh2, hg);

  gemm<false, false>(hg, pre_W, pre_b, logits, GNUM, EMBD, LSEM * VSEM, nullptr, nullptr, stream);
  k_sem<<<(GNUM * LSEM + 255) / 256, 256, 0, stream>>>(logits, gumbel, sel_W, sel_b, msgw);
  gemm<false, false>(msgw, aft_W, aft_b, dis, GNUM, 3 * LSEM, EMBD, nullptr, nullptr, stream);
  gemm<false, true>(dis, hW1, hb1, o1, GNUM, EMBD, 128, nullptr, nullptr, stream);
  gemm<false, true>(o1, hW2, hb2, o2, GNUM, 128, 128, nullptr, nullptr, stream);
  gemm<false, false>(o2, hW3, hb3, out, GNUM, 128, 128, nullptr, nullptr, stream);
}